// Round 4
// baseline (344.461 us; speedup 1.0000x reference)
//
#include <hip/hip_runtime.h>
#include <cstddef>

// Problem dims
#define BATCH 128
#define T1 4096
#define P1 2048
#define T2 2048
#define P2 1024
#define NNODE 1024

// Workspace layout (bytes). Overlays:
//  - Pf/Pg overlay h1 (h1 dead after conv2)
//  - sidx overlays h2 (h2 dead after gat_hw)
//  - weight planes overlay skeys (skeys written by rank, after all weight use)
#define OFF_H1   ((size_t)0)
#define OFF_PF   ((size_t)0)
#define OFF_PG   ((size_t)10496000)
#define OFF_H2   ((size_t)33554432)
#define OFF_SIDX ((size_t)33554432)
#define OFF_HW   ((size_t)67108864)
#define OFF_SSRC ((size_t)75497472)
#define OFF_SDST ((size_t)76021760)
#define OFF_POOL ((size_t)76546048)
#define OFF_SK   ((size_t)76554240)
#define OFF_W1P  ((size_t)76554240)   // 5*32*72*2  = 23040 B (ushort)
#define OFF_W2P  ((size_t)76577280)   // 5*64*104*2 = 66560 B
#define OFF_GWT  ((size_t)76643840)   // 4096 B
// max used: 77,078,528 bytes (same budget as previous rounds)

typedef __attribute__((ext_vector_type(8))) short bf16x8;
typedef __attribute__((ext_vector_type(4))) float f32x4;

__device__ __forceinline__ ushort f2bf(float v) {
    uint u = __float_as_uint(v);
    uint r = u + 0x7FFFu + ((u >> 16) & 1u);
    return (ushort)(r >> 16);
}
__device__ __forceinline__ float bf2f(ushort h) {
    return __uint_as_float(((uint)h) << 16);
}

// ---------------------------------------------------------------------------
// prep: build split-bf16 weight planes.
// w1p[kk][oc][72]: cols 0..16 = w_hi, 17..33 = w_hi, 34..50 = w_lo, 51..71 = 0
// w2p[kk][oc][104]: 0..31 = w_hi, 32..63 = w_hi, 64..95 = w_lo, 96..103 = 0
// gwt[64][16] = gat_w^T (fp32).
__global__ void prep_kernel(const float* __restrict__ w1, const float* __restrict__ w2,
                            const float* __restrict__ gw,
                            ushort* __restrict__ w1p, ushort* __restrict__ w2p,
                            float* __restrict__ gwt)
{
    const int idx0 = blockIdx.x * 256 + threadIdx.x;
    for (int idx = idx0; idx < 5 * 32 * 72; idx += 16 * 256) {
        int ce = idx % 72, oc = (idx / 72) % 32, kk = idx / (72 * 32);
        ushort r = 0;
        if (ce < 51) {
            int c = (ce < 17) ? ce : (ce < 34 ? ce - 17 : ce - 34);
            float v = w1[(oc * 17 + c) * 5 + kk];
            ushort hi = f2bf(v);
            r = (ce < 34) ? hi : f2bf(v - bf2f(hi));
        }
        w1p[idx] = r;
    }
    for (int idx = idx0; idx < 5 * 64 * 104; idx += 16 * 256) {
        int ce = idx % 104, oc = (idx / 104) % 64, kk = idx / (104 * 64);
        ushort r = 0;
        if (ce < 96) {
            int c = (ce < 32) ? ce : (ce < 64 ? ce - 32 : ce - 64);
            float v = w2[(oc * 32 + c) * 5 + kk];
            ushort hi = f2bf(v);
            r = (ce < 64) ? hi : f2bf(v - bf2f(hi));
        }
        w2p[idx] = r;
    }
    for (int idx = idx0; idx < 1024; idx += 16 * 256) {
        int d = idx >> 4, o = idx & 15;
        gwt[idx] = gw[o * 64 + d];
    }
}

// ---------------------------------------------------------------------------
// conv1 (17->32,k5,p2)+relu+pool via MFMA. x:[128,17,4096] -> h1:[128,2048,32] (ch-last)
// Block 256 = 4 waves; wave: 128 prepool x 32 oc; block: 512 prepool. Grid (8,128).
// LDS x rows [t][72 bf16]: [x_hi(17)|x_lo(17)|x_hi(17)|zeros]; kk = row shift.
__global__ __launch_bounds__(256, 2) void conv1_mfma(
    const float* __restrict__ x, const ushort* __restrict__ w1p,
    const float* __restrict__ bias, float* __restrict__ h1)
{
    __shared__ ushort sx[516 * 72];     // 74304 B
    __shared__ ushort sw[32 * 72];      //  4608 B
    const int tid = threadIdx.x;
    const int b = blockIdx.y;
    const int tb = blockIdx.x * 512;

    const float* xb = x + (size_t)b * (17 * T1);
    for (int idx = tid; idx < 516 * 17; idx += 256) {
        int r = idx % 516, c = idx / 516;
        int t = tb + r - 2;
        float v = (t >= 0 && t < T1) ? xb[c * T1 + t] : 0.0f;
        ushort hi = f2bf(v);
        ushort lo = f2bf(v - bf2f(hi));
        sx[r * 72 + c] = hi; sx[r * 72 + 17 + c] = lo; sx[r * 72 + 34 + c] = hi;
    }
    for (int idx = tid; idx < 516 * 13; idx += 256) {   // zero cols 51..63 (NaN guard)
        int r = idx / 13, c = 51 + idx % 13;
        sx[r * 72 + c] = 0;
    }

    const int lane = tid & 63;
    const int wv = tid >> 6;
    const int l15 = lane & 15;
    const int kq = lane >> 4;
    f32x4 acc[8][2];
#pragma unroll
    for (int p = 0; p < 8; p++)
#pragma unroll
        for (int o = 0; o < 2; o++) acc[p][o] = (f32x4){0.f, 0.f, 0.f, 0.f};

    const uint* wsrc = (const uint*)w1p;
    for (int kk = 0; kk < 5; kk++) {
        __syncthreads();
        for (int i = tid; i < 1152; i += 256) ((uint*)sw)[i] = wsrc[kk * 1152 + i];
        __syncthreads();
#pragma unroll
        for (int ks = 0; ks < 2; ks++) {
            const int koff = kq * 8 + ks * 32;
            bf16x8 b0 = *(const bf16x8*)&sw[l15 * 72 + koff];
            bf16x8 b1 = *(const bf16x8*)&sw[(16 + l15) * 72 + koff];
#pragma unroll
            for (int p = 0; p < 8; p++) {
                int row = wv * 128 + p * 16 + l15 + kk;
                bf16x8 a = *(const bf16x8*)&sx[row * 72 + koff];
                acc[p][0] = __builtin_amdgcn_mfma_f32_16x16x32_bf16(a, b0, acc[p][0], 0, 0, 0);
                acc[p][1] = __builtin_amdgcn_mfma_f32_16x16x32_bf16(a, b1, acc[p][1], 0, 0, 0);
            }
        }
    }
    // epilogue: D row = (lane>>4)*4+reg (prepool), col = lane&15 (oc). Pool in-lane.
    const float bo0 = bias[l15], bo1 = bias[16 + l15];
    float* hb1 = h1 + (size_t)b * P1 * 32;
    const int pbase = tb / 2 + wv * 64 + kq * 2;
#pragma unroll
    for (int p = 0; p < 8; p++) {
        int pr = pbase + p * 8;
#pragma unroll
        for (int o = 0; o < 2; o++) {
            float bo = o ? bo1 : bo0;
            float v0 = fmaxf(fmaxf(acc[p][o][0], acc[p][o][1]) + bo, 0.f);
            float v1 = fmaxf(fmaxf(acc[p][o][2], acc[p][o][3]) + bo, 0.f);
            hb1[(size_t)pr * 32 + o * 16 + l15] = v0;
            hb1[(size_t)(pr + 1) * 32 + o * 16 + l15] = v1;
        }
    }
}

// ---------------------------------------------------------------------------
// conv2 (32->64,k5,p2)+relu+pool via MFMA. h1:[128,2048,32] -> h2:[128,1024,64] (ch-last)
// Block 256 = 4 waves; wave: 64 prepool x 64 oc; block: 256 prepool. Grid (8,128).
__global__ __launch_bounds__(256, 2) void conv2_mfma(
    const float* __restrict__ h1, const ushort* __restrict__ w2p,
    const float* __restrict__ bias, float* __restrict__ h2)
{
    __shared__ ushort sx[260 * 104];    // 54080 B
    __shared__ ushort sw[64 * 104];     // 13312 B
    const int tid = threadIdx.x;
    const int b = blockIdx.y;
    const int tb = blockIdx.x * 256;

    const float* hb = h1 + (size_t)b * T2 * 32;
    for (int idx = tid; idx < 260 * 32; idx += 256) {
        int c = idx & 31, r = idx >> 5;
        int t = tb + r - 2;
        float v = (t >= 0 && t < T2) ? hb[(size_t)t * 32 + c] : 0.0f;
        ushort hi = f2bf(v);
        ushort lo = f2bf(v - bf2f(hi));
        sx[r * 104 + c] = hi; sx[r * 104 + 32 + c] = lo; sx[r * 104 + 64 + c] = hi;
    }

    const int lane = tid & 63;
    const int wv = tid >> 6;
    const int l15 = lane & 15;
    const int kq = lane >> 4;
    f32x4 acc[4][4];
#pragma unroll
    for (int p = 0; p < 4; p++)
#pragma unroll
        for (int o = 0; o < 4; o++) acc[p][o] = (f32x4){0.f, 0.f, 0.f, 0.f};

    const uint* wsrc = (const uint*)w2p;
    for (int kk = 0; kk < 5; kk++) {
        __syncthreads();
        for (int i = tid; i < 3328; i += 256) ((uint*)sw)[i] = wsrc[kk * 3328 + i];
        __syncthreads();
#pragma unroll
        for (int ks = 0; ks < 3; ks++) {
            const int koff = kq * 8 + ks * 32;
            bf16x8 bf0 = *(const bf16x8*)&sw[(0 * 16 + l15) * 104 + koff];
            bf16x8 bf1 = *(const bf16x8*)&sw[(1 * 16 + l15) * 104 + koff];
            bf16x8 bf2 = *(const bf16x8*)&sw[(2 * 16 + l15) * 104 + koff];
            bf16x8 bf3 = *(const bf16x8*)&sw[(3 * 16 + l15) * 104 + koff];
#pragma unroll
            for (int p = 0; p < 4; p++) {
                int row = wv * 64 + p * 16 + l15 + kk;
                bf16x8 a = *(const bf16x8*)&sx[row * 104 + koff];
                acc[p][0] = __builtin_amdgcn_mfma_f32_16x16x32_bf16(a, bf0, acc[p][0], 0, 0, 0);
                acc[p][1] = __builtin_amdgcn_mfma_f32_16x16x32_bf16(a, bf1, acc[p][1], 0, 0, 0);
                acc[p][2] = __builtin_amdgcn_mfma_f32_16x16x32_bf16(a, bf2, acc[p][2], 0, 0, 0);
                acc[p][3] = __builtin_amdgcn_mfma_f32_16x16x32_bf16(a, bf3, acc[p][3], 0, 0, 0);
            }
        }
    }
    float* hb2 = h2 + (size_t)b * P2 * 64;
    const int pbase = tb / 2 + wv * 32 + kq * 2;
#pragma unroll
    for (int p = 0; p < 4; p++) {
        int pr = pbase + p * 8;
#pragma unroll
        for (int o = 0; o < 4; o++) {
            int oc = o * 16 + l15;
            float bo = bias[oc];
            float v0 = fmaxf(fmaxf(acc[p][o][0], acc[p][o][1]) + bo, 0.f);
            float v1 = fmaxf(fmaxf(acc[p][o][2], acc[p][o][3]) + bo, 0.f);
            hb2[(size_t)pr * 64 + oc] = v0;
            hb2[(size_t)(pr + 1) * 64 + oc] = v1;
        }
    }
}

// ---------------------------------------------------------------------------
// GAT projection from channel-last h2. LDS tile 256 nodes x 64 ch (pad 68).
// Grid (4,128) x 256.
__global__ __launch_bounds__(256, 2) void gat_hw_kernel(
    const float* __restrict__ h2, const float* __restrict__ gwt,
    const float* __restrict__ att_src, const float* __restrict__ att_dst,
    float* __restrict__ hw, float* __restrict__ s_src, float* __restrict__ s_dst)
{
    __shared__ float sh[256 * 68];      // 69632 B
    const int tid = threadIdx.x, b = blockIdx.y;
    const int nb = blockIdx.x * 256;
    for (int idx = tid; idx < 256 * 64; idx += 256) {
        int n = idx >> 6, c = idx & 63;
        sh[n * 68 + c] = h2[((size_t)b * NNODE + nb + n) * 64 + c];
    }
    __syncthreads();

    float acc[16];
#pragma unroll
    for (int o = 0; o < 16; o++) acc[o] = 0.f;
    const float* row = &sh[tid * 68];
#pragma unroll
    for (int q = 0; q < 16; q++) {
        float4 h4 = *(const float4*)&row[q * 4];
        float hv[4] = {h4.x, h4.y, h4.z, h4.w};
#pragma unroll
        for (int e = 0; e < 4; e++) {
            const float* wp = &gwt[(q * 4 + e) * 16];   // wave-uniform -> s_load
            float4 w0 = *(const float4*)(wp);
            float4 w1 = *(const float4*)(wp + 4);
            float4 w2 = *(const float4*)(wp + 8);
            float4 w3 = *(const float4*)(wp + 12);
            float hvv = hv[e];
            acc[0]  += hvv * w0.x; acc[1]  += hvv * w0.y; acc[2]  += hvv * w0.z; acc[3]  += hvv * w0.w;
            acc[4]  += hvv * w1.x; acc[5]  += hvv * w1.y; acc[6]  += hvv * w1.z; acc[7]  += hvv * w1.w;
            acc[8]  += hvv * w2.x; acc[9]  += hvv * w2.y; acc[10] += hvv * w2.z; acc[11] += hvv * w2.w;
            acc[12] += hvv * w3.x; acc[13] += hvv * w3.y; acc[14] += hvv * w3.z; acc[15] += hvv * w3.w;
        }
    }
    float ss = 0.f, sd = 0.f;
#pragma unroll
    for (int c = 0; c < 16; c++) { ss += acc[c] * att_src[c]; sd += acc[c] * att_dst[c]; }
    const int node = nb + tid;
    float4* hp = (float4*)(hw + ((size_t)b * NNODE + node) * 16);
    hp[0] = make_float4(acc[0], acc[1], acc[2], acc[3]);
    hp[1] = make_float4(acc[4], acc[5], acc[6], acc[7]);
    hp[2] = make_float4(acc[8], acc[9], acc[10], acc[11]);
    hp[3] = make_float4(acc[12], acc[13], acc[14], acc[15]);
    s_src[b * NNODE + node] = ss;
    s_dst[b * NNODE + node] = sd;
}

// ---------------------------------------------------------------------------
// rank: stable sort via rank-count on sortable u64 (key bits || index).
// Grid (4,128) x 256, 1 key/thread.
__global__ __launch_bounds__(256) void rank_kernel(
    const float* __restrict__ s_src, float* __restrict__ skeys, int* __restrict__ sidx)
{
    __shared__ unsigned long long ku[1024];     // 8192 B
    const int tid = threadIdx.x, b = blockIdx.y;
    for (int t = tid; t < 1024; t += 256) {
        uint kb = __float_as_uint(s_src[b * NNODE + t]);
        uint m = (uint)((int)kb >> 31);
        kb = kb ^ (m | 0x80000000u);
        ku[t] = ((unsigned long long)kb << 32) | (uint)t;
    }
    __syncthreads();
    const int j = blockIdx.x * 256 + tid;
    const unsigned long long my = ku[j];
    int r = 0;
    const ulonglong2* kv = (const ulonglong2*)ku;
    for (int u = 0; u < 512; u++) {
        ulonglong2 p = kv[u];
        r += (int)(p.x < my) + (int)(p.y < my);
    }
    skeys[b * NNODE + r] = s_src[b * NNODE + j];
    sidx[b * NNODE + r] = j;
}

// ---------------------------------------------------------------------------
__device__ __forceinline__ void accum17(float* L, float wgt, const float4* hj)
{
    float4 a0 = hj[0], a1 = hj[1], a2 = hj[2], a3 = hj[3];
    L[0]  += wgt * a0.x; L[1]  += wgt * a0.y; L[2]  += wgt * a0.z; L[3]  += wgt * a0.w;
    L[4]  += wgt * a1.x; L[5]  += wgt * a1.y; L[6]  += wgt * a1.z; L[7]  += wgt * a1.w;
    L[8]  += wgt * a2.x; L[9]  += wgt * a2.y; L[10] += wgt * a2.z; L[11] += wgt * a2.w;
    L[12] += wgt * a3.x; L[13] += wgt * a3.y; L[14] += wgt * a3.z; L[15] += wgt * a3.w;
    L[16] += wgt;
}
__device__ __forceinline__ void store17(float* dst, const float* L)
{
    *(float4*)(dst + 0)  = make_float4(L[0],  L[1],  L[2],  L[3]);
    *(float4*)(dst + 4)  = make_float4(L[4],  L[5],  L[6],  L[7]);
    *(float4*)(dst + 8)  = make_float4(L[8],  L[9],  L[10], L[11]);
    *(float4*)(dst + 12) = make_float4(L[12], L[13], L[14], L[15]);
    dst[16] = L[16];
}

// ---------------------------------------------------------------------------
// Fused prefix + apply. One 1024-thread block per batch (grid 128).
// Phase 1: exclusive prefix sums of f/g-weighted [hw,1] over sorted order -> global.
// Phase 2 (same block, after fence): per-row binary search + combine + self-loop
// + block reduce -> pooled[b][16] (no atomics).
__global__ __launch_bounds__(1024) void attn_kernel(
    const float* __restrict__ skeys, const int* __restrict__ sidx,
    const float* __restrict__ s_src, const float* __restrict__ s_dst,
    const float* __restrict__ hw, float* __restrict__ Pf, float* __restrict__ Pg,
    float* __restrict__ pooled)
{
    __shared__ float sks[1024];
    __shared__ float wsum[16][34];
    __shared__ float stot[17];
    __shared__ float sred[16][16];
    const int tid = threadIdx.x, b = blockIdx.x;
    const int lane = tid & 63, wv = tid >> 6;

    const float key = skeys[b * NNODE + tid];
    const int j = sidx[b * NNODE + tid];
    sks[tid] = key;
    __syncthreads();
    const float M = sks[1023];
    const float* hwb = hw + (size_t)b * NNODE * 16;
    const float f = __expf(key - M);
    const float g = __expf(0.2f * (key - M));
    const float4* hj = (const float4*)(hwb + (size_t)j * 16);

    float Lf[17], Lg[17];
#pragma unroll
    for (int c = 0; c < 17; c++) { Lf[c] = 0.f; Lg[c] = 0.f; }
    accum17(Lf, f, hj);
    accum17(Lg, g, hj);

#pragma unroll
    for (int s = 1; s < 64; s <<= 1) {
#pragma unroll
        for (int c = 0; c < 17; c++) {
            float of = __shfl_up(Lf[c], s);
            float og = __shfl_up(Lg[c], s);
            if (lane >= s) { Lf[c] += of; Lg[c] += og; }
        }
    }
    if (lane == 63) {
#pragma unroll
        for (int c = 0; c < 17; c++) { wsum[wv][c] = Lf[c]; wsum[wv][17 + c] = Lg[c]; }
    }
#pragma unroll
    for (int c = 0; c < 17; c++) {
        float ef = __shfl_up(Lf[c], 1);
        float eg = __shfl_up(Lg[c], 1);
        Lf[c] = (lane == 0) ? 0.f : ef;
        Lg[c] = (lane == 0) ? 0.f : eg;
    }
    __syncthreads();
#pragma unroll
    for (int c = 0; c < 17; c++) {
        float bf = 0.f, bg = 0.f;
        for (int w2 = 0; w2 < wv; w2++) { bf += wsum[w2][c]; bg += wsum[w2][17 + c]; }
        Lf[c] += bf; Lg[c] += bg;
    }
    float* pfB = Pf + (size_t)b * (1025 * 20);
    float* pgB = Pg + (size_t)b * (1025 * 20);
    store17(pfB + (size_t)tid * 20, Lf);
    store17(pgB + (size_t)tid * 20, Lg);
    if (tid == 1023) {
        accum17(Lf, f, hj);     // -> inclusive grand totals
        accum17(Lg, g, hj);
        store17(pfB + (size_t)1024 * 20, Lf);
        store17(pgB + (size_t)1024 * 20, Lg);
#pragma unroll
        for (int c = 0; c < 17; c++) stot[c] = Lf[c];
    }
    __threadfence();
    __syncthreads();

    // ---- apply phase (row i = tid) ----
    const float sdi = s_dst[b * NNODE + tid];
    const float ssi = s_src[b * NNODE + tid];
    const float eM = sdi + M;
    const float m_i = (eM >= 0.f) ? eM : 0.2f * eM;
    const float th = -sdi;
    int lo = 0, hi = 1024;
    while (lo < hi) { int mid = (lo + hi) >> 1; if (sks[mid] < th) lo = mid + 1; else hi = mid; }

    const float A  = __expf(eM - m_i);
    const float Bc = __expf(0.2f * eM - m_i);
    const float* pf0 = pfB + (size_t)lo * 20;
    const float* pg0 = pgB + (size_t)lo * 20;
    float acc[17];
#pragma unroll
    for (int c = 0; c < 17; c++) acc[c] = A * (stot[c] - pf0[c]) + Bc * pg0[c];

    float e2 = sdi + ssi;
    float el = (e2 >= 0.f) ? e2 : 0.2f * e2;
    float wii = __expf(el - m_i);
    const float* hi8 = hwb + (size_t)tid * 16;
#pragma unroll
    for (int c = 0; c < 16; c++) acc[c] += wii * hi8[c];
    acc[16] += wii;

    float inv = 1.0f / acc[16];
    float r[16];
#pragma unroll
    for (int c = 0; c < 16; c++) r[c] = acc[c] * inv;
#pragma unroll
    for (int s = 32; s > 0; s >>= 1) {
#pragma unroll
        for (int c = 0; c < 16; c++) r[c] += __shfl_down(r[c], s);
    }
    if (lane == 0) {
#pragma unroll
        for (int c = 0; c < 16; c++) sred[wv][c] = r[c];
    }
    __syncthreads();
    if (tid < 16) {
        float t = 0.f;
#pragma unroll
        for (int w2 = 0; w2 < 16; w2++) t += sred[w2][tid];
        pooled[b * 16 + tid] = t;
    }
}

// ---------------------------------------------------------------------------
__global__ void final_kernel(
    const float* __restrict__ pooled, const float* __restrict__ gat_b,
    const float* __restrict__ fc_w, const float* __restrict__ fc_b,
    float* __restrict__ out)
{
    int b = threadIdx.x;
    if (b >= BATCH) return;
    float o0 = fc_b[0], o1 = fc_b[1];
#pragma unroll
    for (int d = 0; d < 16; d++) {
        float pv = pooled[b * 16 + d] * (1.0f / 1024.0f) + gat_b[d];
        o0 += pv * fc_w[d];
        o1 += pv * fc_w[16 + d];
    }
    out[2 * b] = o0;
    out[2 * b + 1] = o1;
}

// ---------------------------------------------------------------------------
extern "C" void kernel_launch(void* const* d_in, const int* in_sizes, int n_in,
                              void* d_out, int out_size, void* d_ws, size_t ws_size,
                              hipStream_t stream)
{
    (void)in_sizes; (void)n_in; (void)out_size; (void)ws_size;
    const float* x       = (const float*)d_in[0];
    const float* conv1_w = (const float*)d_in[1];
    const float* conv1_b = (const float*)d_in[2];
    const float* conv2_w = (const float*)d_in[3];
    const float* conv2_b = (const float*)d_in[4];
    const float* gat_w   = (const float*)d_in[5];
    const float* att_src = (const float*)d_in[6];
    const float* att_dst = (const float*)d_in[7];
    const float* gat_b   = (const float*)d_in[8];
    const float* fc_w    = (const float*)d_in[9];
    const float* fc_b    = (const float*)d_in[10];
    float* out = (float*)d_out;

    char* ws = (char*)d_ws;
    float*  h1    = (float*)(ws + OFF_H1);
    float*  h2    = (float*)(ws + OFF_H2);
    float*  hw    = (float*)(ws + OFF_HW);
    ushort* w1p   = (ushort*)(ws + OFF_W1P);
    ushort* w2p   = (ushort*)(ws + OFF_W2P);
    float*  gwt   = (float*)(ws + OFF_GWT);
    float*  ssrc  = (float*)(ws + OFF_SSRC);
    float*  sdst  = (float*)(ws + OFF_SDST);
    float*  pool  = (float*)(ws + OFF_POOL);
    float*  skeys = (float*)(ws + OFF_SK);
    int*    sidx  = (int*)(ws + OFF_SIDX);
    float*  Pf    = (float*)(ws + OFF_PF);
    float*  Pg    = (float*)(ws + OFF_PG);

    hipLaunchKernelGGL(prep_kernel, dim3(16), dim3(256), 0, stream,
                       conv1_w, conv2_w, gat_w, w1p, w2p, gwt);
    hipLaunchKernelGGL(conv1_mfma, dim3(8, BATCH), dim3(256), 0, stream,
                       x, w1p, conv1_b, h1);
    hipLaunchKernelGGL(conv2_mfma, dim3(8, BATCH), dim3(256), 0, stream,
                       h1, w2p, conv2_b, h2);
    hipLaunchKernelGGL(gat_hw_kernel, dim3(4, BATCH), dim3(256), 0, stream,
                       h2, gwt, att_src, att_dst, hw, ssrc, sdst);
    hipLaunchKernelGGL(rank_kernel, dim3(4, BATCH), dim3(256), 0, stream,
                       ssrc, skeys, sidx);
    hipLaunchKernelGGL(attn_kernel, dim3(BATCH), dim3(1024), 0, stream,
                       skeys, sidx, ssrc, sdst, hw, Pf, Pg, pool);
    hipLaunchKernelGGL(final_kernel, dim3(1), dim3(128), 0, stream,
                       pool, gat_b, fc_w, fc_b, out);
}

// Round 6
// 281.667 us; speedup vs baseline: 1.2229x; 1.2229x over previous
//
#include <hip/hip_runtime.h>
#include <cstddef>

// Problem dims
#define BATCH 128
#define T1 4096
#define P1 2048
#define T2 2048
#define P2 1024
#define NNODE 1024

// Workspace layout (bytes). Overlays:
//  - ski (sorted key+idx, 1 MB) overlays h1 (h1 dead after conv2; rank runs after)
//  - weight planes live past OFF_POOL (written by prep, read by convs/gat only)
#define OFF_H1   ((size_t)0)
#define OFF_SKI  ((size_t)0)
#define OFF_H2   ((size_t)33554432)
#define OFF_HW   ((size_t)67108864)
#define OFF_SSRC ((size_t)75497472)
#define OFF_SDST ((size_t)76021760)
#define OFF_POOL ((size_t)76546048)
#define OFF_W1P  ((size_t)76554240)   // 5*32*72*2  = 23040 B (ushort)
#define OFF_W2P  ((size_t)76577280)   // 5*64*104*2 = 66560 B
#define OFF_GWT  ((size_t)76643840)   // 4096 B
// max used: 76,647,936 bytes (within prior 77,078,528 budget)

typedef __attribute__((ext_vector_type(8))) short bf16x8;
typedef __attribute__((ext_vector_type(4))) float f32x4;

__device__ __forceinline__ ushort f2bf(float v) {
    uint u = __float_as_uint(v);
    uint r = u + 0x7FFFu + ((u >> 16) & 1u);
    return (ushort)(r >> 16);
}
__device__ __forceinline__ float bf2f(ushort h) {
    return __uint_as_float(((uint)h) << 16);
}

// ---------------------------------------------------------------------------
// prep: split-bf16 weight planes + gat_w transpose.
__global__ void prep_kernel(const float* __restrict__ w1, const float* __restrict__ w2,
                            const float* __restrict__ gw,
                            ushort* __restrict__ w1p, ushort* __restrict__ w2p,
                            float* __restrict__ gwt)
{
    const int idx0 = blockIdx.x * 256 + threadIdx.x;
    for (int idx = idx0; idx < 5 * 32 * 72; idx += 16 * 256) {
        int ce = idx % 72, oc = (idx / 72) % 32, kk = idx / (72 * 32);
        ushort r = 0;
        if (ce < 51) {
            int c = (ce < 17) ? ce : (ce < 34 ? ce - 17 : ce - 34);
            float v = w1[(oc * 17 + c) * 5 + kk];
            ushort hi = f2bf(v);
            r = (ce < 34) ? hi : f2bf(v - bf2f(hi));
        }
        w1p[idx] = r;
    }
    for (int idx = idx0; idx < 5 * 64 * 104; idx += 16 * 256) {
        int ce = idx % 104, oc = (idx / 104) % 64, kk = idx / (104 * 64);
        ushort r = 0;
        if (ce < 96) {
            int c = (ce < 32) ? ce : (ce < 64 ? ce - 32 : ce - 64);
            float v = w2[(oc * 32 + c) * 5 + kk];
            ushort hi = f2bf(v);
            r = (ce < 64) ? hi : f2bf(v - bf2f(hi));
        }
        w2p[idx] = r;
    }
    for (int idx = idx0; idx < 1024; idx += 16 * 256) {
        int d = idx >> 4, o = idx & 15;
        gwt[idx] = gw[o * 64 + d];
    }
}

// ---------------------------------------------------------------------------
// conv1 (17->32,k5,p2)+relu+pool via MFMA. x:[128,17,4096] -> h1:[128,2048,32] (ch-last)
__global__ __launch_bounds__(256, 2) void conv1_mfma(
    const float* __restrict__ x, const ushort* __restrict__ w1p,
    const float* __restrict__ bias, float* __restrict__ h1)
{
    __shared__ ushort sx[516 * 72];     // 74304 B
    __shared__ ushort sw[32 * 72];      //  4608 B
    const int tid = threadIdx.x;
    const int b = blockIdx.y;
    const int tb = blockIdx.x * 512;

    const float* xb = x + (size_t)b * (17 * T1);
    for (int idx = tid; idx < 516 * 17; idx += 256) {
        int r = idx % 516, c = idx / 516;
        int t = tb + r - 2;
        float v = (t >= 0 && t < T1) ? xb[c * T1 + t] : 0.0f;
        ushort hi = f2bf(v);
        ushort lo = f2bf(v - bf2f(hi));
        sx[r * 72 + c] = hi; sx[r * 72 + 17 + c] = lo; sx[r * 72 + 34 + c] = hi;
    }
    for (int idx = tid; idx < 516 * 13; idx += 256) {   // zero cols 51..63 (NaN guard)
        int r = idx / 13, c = 51 + idx % 13;
        sx[r * 72 + c] = 0;
    }

    const int lane = tid & 63;
    const int wv = tid >> 6;
    const int l15 = lane & 15;
    const int kq = lane >> 4;
    f32x4 acc[8][2];
#pragma unroll
    for (int p = 0; p < 8; p++)
#pragma unroll
        for (int o = 0; o < 2; o++) acc[p][o] = (f32x4){0.f, 0.f, 0.f, 0.f};

    const uint* wsrc = (const uint*)w1p;
    for (int kk = 0; kk < 5; kk++) {
        __syncthreads();
        for (int i = tid; i < 1152; i += 256) ((uint*)sw)[i] = wsrc[kk * 1152 + i];
        __syncthreads();
#pragma unroll
        for (int ks = 0; ks < 2; ks++) {
            const int koff = kq * 8 + ks * 32;
            bf16x8 b0 = *(const bf16x8*)&sw[l15 * 72 + koff];
            bf16x8 b1 = *(const bf16x8*)&sw[(16 + l15) * 72 + koff];
#pragma unroll
            for (int p = 0; p < 8; p++) {
                int row = wv * 128 + p * 16 + l15 + kk;
                bf16x8 a = *(const bf16x8*)&sx[row * 72 + koff];
                acc[p][0] = __builtin_amdgcn_mfma_f32_16x16x32_bf16(a, b0, acc[p][0], 0, 0, 0);
                acc[p][1] = __builtin_amdgcn_mfma_f32_16x16x32_bf16(a, b1, acc[p][1], 0, 0, 0);
            }
        }
    }
    const float bo0 = bias[l15], bo1 = bias[16 + l15];
    float* hb1 = h1 + (size_t)b * P1 * 32;
    const int pbase = tb / 2 + wv * 64 + kq * 2;
#pragma unroll
    for (int p = 0; p < 8; p++) {
        int pr = pbase + p * 8;
#pragma unroll
        for (int o = 0; o < 2; o++) {
            float bo = o ? bo1 : bo0;
            float v0 = fmaxf(fmaxf(acc[p][o][0], acc[p][o][1]) + bo, 0.f);
            float v1 = fmaxf(fmaxf(acc[p][o][2], acc[p][o][3]) + bo, 0.f);
            hb1[(size_t)pr * 32 + o * 16 + l15] = v0;
            hb1[(size_t)(pr + 1) * 32 + o * 16 + l15] = v1;
        }
    }
}

// ---------------------------------------------------------------------------
// conv2 (32->64,k5,p2)+relu+pool via MFMA. h1:[128,2048,32] -> h2:[128,1024,64]
__global__ __launch_bounds__(256, 2) void conv2_mfma(
    const float* __restrict__ h1, const ushort* __restrict__ w2p,
    const float* __restrict__ bias, float* __restrict__ h2)
{
    __shared__ ushort sx[260 * 104];    // 54080 B
    __shared__ ushort sw[64 * 104];     // 13312 B
    const int tid = threadIdx.x;
    const int b = blockIdx.y;
    const int tb = blockIdx.x * 256;

    const float* hb = h1 + (size_t)b * T2 * 32;
    for (int idx = tid; idx < 260 * 32; idx += 256) {
        int c = idx & 31, r = idx >> 5;
        int t = tb + r - 2;
        float v = (t >= 0 && t < T2) ? hb[(size_t)t * 32 + c] : 0.0f;
        ushort hi = f2bf(v);
        ushort lo = f2bf(v - bf2f(hi));
        sx[r * 104 + c] = hi; sx[r * 104 + 32 + c] = lo; sx[r * 104 + 64 + c] = hi;
    }

    const int lane = tid & 63;
    const int wv = tid >> 6;
    const int l15 = lane & 15;
    const int kq = lane >> 4;
    f32x4 acc[4][4];
#pragma unroll
    for (int p = 0; p < 4; p++)
#pragma unroll
        for (int o = 0; o < 4; o++) acc[p][o] = (f32x4){0.f, 0.f, 0.f, 0.f};

    const uint* wsrc = (const uint*)w2p;
    for (int kk = 0; kk < 5; kk++) {
        __syncthreads();
        for (int i = tid; i < 3328; i += 256) ((uint*)sw)[i] = wsrc[kk * 3328 + i];
        __syncthreads();
#pragma unroll
        for (int ks = 0; ks < 3; ks++) {
            const int koff = kq * 8 + ks * 32;
            bf16x8 bf0 = *(const bf16x8*)&sw[(0 * 16 + l15) * 104 + koff];
            bf16x8 bf1 = *(const bf16x8*)&sw[(1 * 16 + l15) * 104 + koff];
            bf16x8 bf2 = *(const bf16x8*)&sw[(2 * 16 + l15) * 104 + koff];
            bf16x8 bf3 = *(const bf16x8*)&sw[(3 * 16 + l15) * 104 + koff];
#pragma unroll
            for (int p = 0; p < 4; p++) {
                int row = wv * 64 + p * 16 + l15 + kk;
                bf16x8 a = *(const bf16x8*)&sx[row * 104 + koff];
                acc[p][0] = __builtin_amdgcn_mfma_f32_16x16x32_bf16(a, bf0, acc[p][0], 0, 0, 0);
                acc[p][1] = __builtin_amdgcn_mfma_f32_16x16x32_bf16(a, bf1, acc[p][1], 0, 0, 0);
                acc[p][2] = __builtin_amdgcn_mfma_f32_16x16x32_bf16(a, bf2, acc[p][2], 0, 0, 0);
                acc[p][3] = __builtin_amdgcn_mfma_f32_16x16x32_bf16(a, bf3, acc[p][3], 0, 0, 0);
            }
        }
    }
    float* hb2 = h2 + (size_t)b * P2 * 64;
    const int pbase = tb / 2 + wv * 32 + kq * 2;
#pragma unroll
    for (int p = 0; p < 4; p++) {
        int pr = pbase + p * 8;
#pragma unroll
        for (int o = 0; o < 4; o++) {
            int oc = o * 16 + l15;
            float bo = bias[oc];
            float v0 = fmaxf(fmaxf(acc[p][o][0], acc[p][o][1]) + bo, 0.f);
            float v1 = fmaxf(fmaxf(acc[p][o][2], acc[p][o][3]) + bo, 0.f);
            hb2[(size_t)pr * 64 + oc] = v0;
            hb2[(size_t)(pr + 1) * 64 + oc] = v1;
        }
    }
}

// ---------------------------------------------------------------------------
// GAT projection from channel-last h2. Grid (4,128) x 256.
__global__ __launch_bounds__(256, 2) void gat_hw_kernel(
    const float* __restrict__ h2, const float* __restrict__ gwt,
    const float* __restrict__ att_src, const float* __restrict__ att_dst,
    float* __restrict__ hw, float* __restrict__ s_src, float* __restrict__ s_dst)
{
    __shared__ float sh[256 * 68];      // 69632 B
    const int tid = threadIdx.x, b = blockIdx.y;
    const int nb = blockIdx.x * 256;
    for (int idx = tid; idx < 256 * 64; idx += 256) {
        int n = idx >> 6, c = idx & 63;
        sh[n * 68 + c] = h2[((size_t)b * NNODE + nb + n) * 64 + c];
    }
    __syncthreads();

    float acc[16];
#pragma unroll
    for (int o = 0; o < 16; o++) acc[o] = 0.f;
    const float* row = &sh[tid * 68];
#pragma unroll
    for (int q = 0; q < 16; q++) {
        float4 h4 = *(const float4*)&row[q * 4];
        float hv[4] = {h4.x, h4.y, h4.z, h4.w};
#pragma unroll
        for (int e = 0; e < 4; e++) {
            const float* wp = &gwt[(q * 4 + e) * 16];   // wave-uniform -> s_load
            float4 w0 = *(const float4*)(wp);
            float4 w1 = *(const float4*)(wp + 4);
            float4 w2 = *(const float4*)(wp + 8);
            float4 w3 = *(const float4*)(wp + 12);
            float hvv = hv[e];
            acc[0]  += hvv * w0.x; acc[1]  += hvv * w0.y; acc[2]  += hvv * w0.z; acc[3]  += hvv * w0.w;
            acc[4]  += hvv * w1.x; acc[5]  += hvv * w1.y; acc[6]  += hvv * w1.z; acc[7]  += hvv * w1.w;
            acc[8]  += hvv * w2.x; acc[9]  += hvv * w2.y; acc[10] += hvv * w2.z; acc[11] += hvv * w2.w;
            acc[12] += hvv * w3.x; acc[13] += hvv * w3.y; acc[14] += hvv * w3.z; acc[15] += hvv * w3.w;
        }
    }
    float ss = 0.f, sd = 0.f;
#pragma unroll
    for (int c = 0; c < 16; c++) { ss += acc[c] * att_src[c]; sd += acc[c] * att_dst[c]; }
    const int node = nb + tid;
    float4* hp = (float4*)(hw + ((size_t)b * NNODE + node) * 16);
    hp[0] = make_float4(acc[0], acc[1], acc[2], acc[3]);
    hp[1] = make_float4(acc[4], acc[5], acc[6], acc[7]);
    hp[2] = make_float4(acc[8], acc[9], acc[10], acc[11]);
    hp[3] = make_float4(acc[12], acc[13], acc[14], acc[15]);
    s_src[b * NNODE + node] = ss;
    s_dst[b * NNODE + node] = sd;
}

// ---------------------------------------------------------------------------
// rank: stable rank-count; candidate stream is wave-uniform -> scalar cache,
// count in VALU. No LDS/VMEM in the loop. Grid (4,128) x 256.
__global__ __launch_bounds__(256) void rank_kernel(
    const float* __restrict__ s_src, float2* __restrict__ ski)
{
    const int tid = threadIdx.x, b = blockIdx.y;
    const int j = blockIdx.x * 256 + tid;
    const float k = s_src[b * NNODE + j];
    const float4* cand = (const float4*)(s_src + b * NNODE);
    int r = 0;
#pragma unroll 4
    for (int u4 = 0; u4 < 256; u4++) {
        const float4 c = cand[u4];          // uniform address -> s_load_dwordx4
        const int u = u4 * 4;
        r += (c.x < k || (c.x == k && (u + 0) < j));
        r += (c.y < k || (c.y == k && (u + 1) < j));
        r += (c.z < k || (c.z == k && (u + 2) < j));
        r += (c.w < k || (c.w == k && (u + 3) < j));
    }
    ski[b * NNODE + r] = make_float2(k, __int_as_float(j));
}

// ---------------------------------------------------------------------------
__device__ __forceinline__ void accum17(float* L, float wgt, const float4* hj)
{
    float4 a0 = hj[0], a1 = hj[1], a2 = hj[2], a3 = hj[3];
    L[0]  += wgt * a0.x; L[1]  += wgt * a0.y; L[2]  += wgt * a0.z; L[3]  += wgt * a0.w;
    L[4]  += wgt * a1.x; L[5]  += wgt * a1.y; L[6]  += wgt * a1.z; L[7]  += wgt * a1.w;
    L[8]  += wgt * a2.x; L[9]  += wgt * a2.y; L[10] += wgt * a2.z; L[11] += wgt * a2.w;
    L[12] += wgt * a3.x; L[13] += wgt * a3.y; L[14] += wgt * a3.z; L[15] += wgt * a3.w;
    L[16] += wgt;
}

// ---------------------------------------------------------------------------
// Fused prefix + apply, fully LDS-resident (no global prefix arrays).
// One 512-thread block per batch (grid 128). LDS ~145 KB -> 1 block/CU.
__global__ __launch_bounds__(512) void attn_kernel(
    const float2* __restrict__ ski, const float* __restrict__ s_src,
    const float* __restrict__ s_dst, const float* __restrict__ hw,
    float* __restrict__ pooled)
{
    __shared__ float sPf[1025][17];     // 69700 B
    __shared__ float sPg[1025][17];     // 69700 B
    __shared__ float sks[1024];
    __shared__ float wsum[8][34];
    __shared__ float sred[8][16];
    const int tid = threadIdx.x, b = blockIdx.x;
    const int lane = tid & 63, wv = tid >> 6;

    const float2 kj0 = ski[b * NNODE + 2 * tid];
    const float2 kj1 = ski[b * NNODE + 2 * tid + 1];
    sks[2 * tid] = kj0.x;
    sks[2 * tid + 1] = kj1.x;
    __syncthreads();
    const float M = sks[1023];
    const float* hwb = hw + (size_t)b * NNODE * 16;
    const int j0 = __float_as_int(kj0.y), j1 = __float_as_int(kj1.y);
    const float f0 = __expf(kj0.x - M), g0 = __expf(0.2f * (kj0.x - M));
    const float f1 = __expf(kj1.x - M), g1 = __expf(0.2f * (kj1.x - M));
    const float4* hj0 = (const float4*)(hwb + (size_t)j0 * 16);
    const float4* hj1 = (const float4*)(hwb + (size_t)j1 * 16);

    float Lf[17], Lg[17];
#pragma unroll
    for (int c = 0; c < 17; c++) { Lf[c] = 0.f; Lg[c] = 0.f; }
    accum17(Lf, f0, hj0); accum17(Lg, g0, hj0);
    accum17(Lf, f1, hj1); accum17(Lg, g1, hj1);

    // wave inclusive scan of per-thread (2-elem) sums
#pragma unroll
    for (int s = 1; s < 64; s <<= 1) {
#pragma unroll
        for (int c = 0; c < 17; c++) {
            float of = __shfl_up(Lf[c], s);
            float og = __shfl_up(Lg[c], s);
            if (lane >= s) { Lf[c] += of; Lg[c] += og; }
        }
    }
    if (lane == 63) {
#pragma unroll
        for (int c = 0; c < 17; c++) { wsum[wv][c] = Lf[c]; wsum[wv][17 + c] = Lg[c]; }
    }
#pragma unroll
    for (int c = 0; c < 17; c++) {   // inclusive -> exclusive
        float ef = __shfl_up(Lf[c], 1);
        float eg = __shfl_up(Lg[c], 1);
        Lf[c] = (lane == 0) ? 0.f : ef;
        Lg[c] = (lane == 0) ? 0.f : eg;
    }
    __syncthreads();
#pragma unroll
    for (int c = 0; c < 17; c++) {   // add totals of preceding waves
        float bf = 0.f, bg = 0.f;
        for (int w2 = 0; w2 < wv; w2++) { bf += wsum[w2][c]; bg += wsum[w2][17 + c]; }
        Lf[c] += bf; Lg[c] += bg;
    }

    // emit exclusive prefix rows into LDS
    const int p0 = 2 * tid;
#pragma unroll
    for (int c = 0; c < 17; c++) { sPf[p0][c] = Lf[c]; sPg[p0][c] = Lg[c]; }
    accum17(Lf, f0, hj0); accum17(Lg, g0, hj0);
#pragma unroll
    for (int c = 0; c < 17; c++) { sPf[p0 + 1][c] = Lf[c]; sPg[p0 + 1][c] = Lg[c]; }
    accum17(Lf, f1, hj1); accum17(Lg, g1, hj1);
    if (tid == 511) {
#pragma unroll
        for (int c = 0; c < 17; c++) { sPf[1024][c] = Lf[c]; sPg[1024][c] = Lg[c]; }
    }
    __syncthreads();

    // ---- apply phase: rows i = tid and tid + 512 ----
    float r[16];
#pragma unroll
    for (int c = 0; c < 16; c++) r[c] = 0.f;
#pragma unroll
    for (int e = 0; e < 2; e++) {
        const int i = e * 512 + tid;
        const float sdi = s_dst[b * NNODE + i];
        const float ssi = s_src[b * NNODE + i];
        const float eM = sdi + M;
        const float m_i = (eM >= 0.f) ? eM : 0.2f * eM;
        const float th = -sdi;
        int lo = 0, hi2 = 1024;
        while (lo < hi2) { int mid = (lo + hi2) >> 1; if (sks[mid] < th) lo = mid + 1; else hi2 = mid; }

        const float A  = __expf(eM - m_i);
        const float Bc = __expf(0.2f * eM - m_i);
        float acc[17];
#pragma unroll
        for (int c = 0; c < 17; c++) acc[c] = A * (sPf[1024][c] - sPf[lo][c]) + Bc * sPg[lo][c];

        float e2 = sdi + ssi;
        float el = (e2 >= 0.f) ? e2 : 0.2f * e2;
        float wii = __expf(el - m_i);
        const float4* hi4 = (const float4*)(hwb + (size_t)i * 16);
        accum17(acc, wii, hi4);

        float inv = 1.0f / acc[16];
#pragma unroll
        for (int c = 0; c < 16; c++) r[c] += acc[c] * inv;
    }
#pragma unroll
    for (int s = 32; s > 0; s >>= 1) {
#pragma unroll
        for (int c = 0; c < 16; c++) r[c] += __shfl_down(r[c], s);
    }
    if (lane == 0) {
#pragma unroll
        for (int c = 0; c < 16; c++) sred[wv][c] = r[c];
    }
    __syncthreads();
    if (tid < 16) {
        float t = 0.f;
#pragma unroll
        for (int w2 = 0; w2 < 8; w2++) t += sred[w2][tid];
        pooled[b * 16 + tid] = t;
    }
}

// ---------------------------------------------------------------------------
__global__ void final_kernel(
    const float* __restrict__ pooled, const float* __restrict__ gat_b,
    const float* __restrict__ fc_w, const float* __restrict__ fc_b,
    float* __restrict__ out)
{
    int b = threadIdx.x;
    if (b >= BATCH) return;
    float o0 = fc_b[0], o1 = fc_b[1];
#pragma unroll
    for (int d = 0; d < 16; d++) {
        float pv = pooled[b * 16 + d] * (1.0f / 1024.0f) + gat_b[d];
        o0 += pv * fc_w[d];
        o1 += pv * fc_w[16 + d];
    }
    out[2 * b] = o0;
    out[2 * b + 1] = o1;
}

// ---------------------------------------------------------------------------
extern "C" void kernel_launch(void* const* d_in, const int* in_sizes, int n_in,
                              void* d_out, int out_size, void* d_ws, size_t ws_size,
                              hipStream_t stream)
{
    (void)in_sizes; (void)n_in; (void)out_size; (void)ws_size;
    const float* x       = (const float*)d_in[0];
    const float* conv1_w = (const float*)d_in[1];
    const float* conv1_b = (const float*)d_in[2];
    const float* conv2_w = (const float*)d_in[3];
    const float* conv2_b = (const float*)d_in[4];
    const float* gat_w   = (const float*)d_in[5];
    const float* att_src = (const float*)d_in[6];
    const float* att_dst = (const float*)d_in[7];
    const float* gat_b   = (const float*)d_in[8];
    const float* fc_w    = (const float*)d_in[9];
    const float* fc_b    = (const float*)d_in[10];
    float* out = (float*)d_out;

    char* ws = (char*)d_ws;
    float*  h1    = (float*)(ws + OFF_H1);
    float*  h2    = (float*)(ws + OFF_H2);
    float*  hw    = (float*)(ws + OFF_HW);
    ushort* w1p   = (ushort*)(ws + OFF_W1P);
    ushort* w2p   = (ushort*)(ws + OFF_W2P);
    float*  gwt   = (float*)(ws + OFF_GWT);
    float*  ssrc  = (float*)(ws + OFF_SSRC);
    float*  sdst  = (float*)(ws + OFF_SDST);
    float*  pool  = (float*)(ws + OFF_POOL);
    float2* ski   = (float2*)(ws + OFF_SKI);

    hipLaunchKernelGGL(prep_kernel, dim3(16), dim3(256), 0, stream,
                       conv1_w, conv2_w, gat_w, w1p, w2p, gwt);
    hipLaunchKernelGGL(conv1_mfma, dim3(8, BATCH), dim3(256), 0, stream,
                       x, w1p, conv1_b, h1);
    hipLaunchKernelGGL(conv2_mfma, dim3(8, BATCH), dim3(256), 0, stream,
                       h1, w2p, conv2_b, h2);
    hipLaunchKernelGGL(gat_hw_kernel, dim3(4, BATCH), dim3(256), 0, stream,
                       h2, gwt, att_src, att_dst, hw, ssrc, sdst);
    hipLaunchKernelGGL(rank_kernel, dim3(4, BATCH), dim3(256), 0, stream,
                       ssrc, ski);
    hipLaunchKernelGGL(attn_kernel, dim3(BATCH), dim3(512), 0, stream,
                       ski, ssrc, sdst, hw, pool);
    hipLaunchKernelGGL(final_kernel, dim3(1), dim3(128), 0, stream,
                       pool, gat_b, fc_w, fc_b, out);
}

// Round 8
// 238.726 us; speedup vs baseline: 1.4429x; 1.1799x over previous
//
#include <hip/hip_runtime.h>
#include <cstddef>

// Problem dims
#define BATCH 128
#define T1 4096
#define P1 2048
#define T2 2048
#define P2 1024
#define NNODE 1024
#define H1ROWS 2052   // 2048 prepool rows + 2 guard rows each side

// Workspace layout (bytes).
//  - ski overlays h1u (h1u dead after conv2; rank runs after gat_hw)
#define OFF_H1U  ((size_t)0)          // 128*2052*64*2 = 33,619,968
#define OFF_SKI  ((size_t)0)
#define OFF_H2   ((size_t)33619968)   // 33,554,432
#define OFF_HW   ((size_t)67174400)   // 8,388,608
#define OFF_SSRC ((size_t)75563008)   // 524,288
#define OFF_SDST ((size_t)76087296)   // 524,288
#define OFF_POOL ((size_t)76611584)   // 8,192
#define OFF_W1P  ((size_t)76619776)   // 5*2*1024*2  = 20,480
#define OFF_W2P  ((size_t)76640256)   // 5*3*2048*2  = 61,440
#define OFF_GWT  ((size_t)76701696)   // 4,096
// end: 76,705,792 (within 77,078,528 budget used previously)

typedef __attribute__((ext_vector_type(8))) short bf16x8;
typedef __attribute__((ext_vector_type(4))) float f32x4;

__device__ __forceinline__ ushort f2bf(float v) {
    uint u = __float_as_uint(v);
    uint r = u + 0x7FFFu + ((u >> 16) & 1u);
    return (ushort)(r >> 16);
}
__device__ __forceinline__ float bf2f(ushort h) {
    return __uint_as_float(((uint)h) << 16);
}

// ---------------------------------------------------------------------------
// prep: fragment-contiguous split-bf16 weight tables + gat_w transpose +
// h1u guard-row zeroing.
// w1p2[kk][ks][o][l15][ke]: K-elem kappa = ks*32+ke of oc=o*16+l15:
//   kappa<17: hi(w1[oc][kappa]); <34: hi(w1[oc][kappa-17]); <51: lo(w1[oc][kappa-34]); else 0
// w2p2[kk][ks][o][l15][ke]: c=ke; ks<2 -> hi(w2[oc][c]), ks==2 -> lo(w2[oc][c])
__global__ void prep_kernel(const float* __restrict__ w1, const float* __restrict__ w2,
                            const float* __restrict__ gw,
                            ushort* __restrict__ w1p2, ushort* __restrict__ w2p2,
                            float* __restrict__ gwt, uint* __restrict__ h1u32)
{
    const int idx0 = blockIdx.x * 256 + threadIdx.x;
    const int stride = 32 * 256;
    for (int idx = idx0; idx < 10240; idx += stride) {      // w1p2
        int kk = idx >> 11, q = idx & 2047;
        int ks = q >> 10, q2 = q & 1023;
        int o = q2 >> 9, r5 = q2 & 511;
        int l15 = r5 >> 5, ke = r5 & 31;
        int oc = o * 16 + l15, kp = ks * 32 + ke;
        ushort r = 0;
        if (kp < 51) {
            int c = (kp < 17) ? kp : (kp < 34 ? kp - 17 : kp - 34);
            float v = w1[(oc * 17 + c) * 5 + kk];
            ushort hi = f2bf(v);
            r = (kp < 34) ? hi : f2bf(v - bf2f(hi));
        }
        w1p2[idx] = r;
    }
    for (int idx = idx0; idx < 30720; idx += stride) {      // w2p2
        int kk = idx / 6144, rem = idx % 6144;
        int ks = rem >> 11, q2 = rem & 2047;
        int o = q2 >> 9, r5 = q2 & 511;
        int l15 = r5 >> 5, c = r5 & 31;
        int oc = o * 16 + l15;
        float v = w2[(oc * 32 + c) * 5 + kk];
        ushort hi = f2bf(v);
        w2p2[idx] = (ks < 2) ? hi : f2bf(v - bf2f(hi));
    }
    for (int idx = idx0; idx < 1024; idx += stride) {       // gwt
        int d = idx >> 4, o = idx & 15;
        gwt[idx] = gw[o * 64 + d];
    }
    for (int idx = idx0; idx < 16384; idx += stride) {      // h1u guard rows = 0
        int b = idx >> 7, rr = (idx >> 5) & 3, col = idx & 31;
        int row = (rr < 2) ? rr : (2048 + rr);
        h1u32[((size_t)b * H1ROWS + row) * 32 + col] = 0;
    }
}

// ---------------------------------------------------------------------------
// conv1 (17->32,k5,p2)+relu+pool via MFMA. x:[128,17,4096] -> h1u split-bf16
// [128][2052][64] (cols 0-31 hi, 32-63 lo; +2 guard offset on rows).
// Block 256 = 4 waves; wave = 64 prepool x 32 oc. Grid (16,128). One barrier.
__global__ __launch_bounds__(256, 4) void conv1_mfma(
    const float* __restrict__ x, const ushort* __restrict__ w1p2,
    const float* __restrict__ bias, ushort* __restrict__ h1u)
{
    __shared__ ushort sx[260 * 72];     // 37440 B
    const int tid = threadIdx.x;
    const int b = blockIdx.y;
    const int tb = blockIdx.x * 256;

    const float* xb = x + (size_t)b * (17 * T1);
    for (int idx = tid; idx < 260 * 17; idx += 256) {
        int r = idx % 260, c = idx / 260;
        int t = tb + r - 2;
        float v = (t >= 0 && t < T1) ? xb[c * T1 + t] : 0.0f;
        ushort hi = f2bf(v);
        ushort lo = f2bf(v - bf2f(hi));
        sx[r * 72 + c] = hi; sx[r * 72 + 17 + c] = lo; sx[r * 72 + 34 + c] = hi;
    }
    for (int idx = tid; idx < 260 * 13; idx += 256) {   // zero K cols 51..63
        int r = idx / 13, c = 51 + idx % 13;
        sx[r * 72 + c] = 0;
    }
    __syncthreads();

    const int lane = tid & 63;
    const int wv = __builtin_amdgcn_readfirstlane(tid >> 6);
    const int l15 = lane & 15;
    const int kq = lane >> 4;
    f32x4 acc[4][2];
#pragma unroll
    for (int p = 0; p < 4; p++)
#pragma unroll
        for (int o = 0; o < 2; o++) acc[p][o] = (f32x4){0.f, 0.f, 0.f, 0.f};

    const ushort* wb = w1p2 + l15 * 32 + kq * 8;
#pragma unroll
    for (int kk = 0; kk < 5; kk++) {
#pragma unroll
        for (int ks = 0; ks < 2; ks++) {
            bf16x8 B0 = *(const bf16x8*)(wb + (kk * 2 + ks) * 1024);
            bf16x8 B1 = *(const bf16x8*)(wb + (kk * 2 + ks) * 1024 + 512);
#pragma unroll
            for (int p = 0; p < 4; p++) {
                int row = wv * 64 + p * 16 + l15 + kk;
                bf16x8 a = *(const bf16x8*)&sx[row * 72 + ks * 32 + kq * 8];
                acc[p][0] = __builtin_amdgcn_mfma_f32_16x16x32_bf16(a, B0, acc[p][0], 0, 0, 0);
                acc[p][1] = __builtin_amdgcn_mfma_f32_16x16x32_bf16(a, B1, acc[p][1], 0, 0, 0);
            }
        }
    }
    const float bo0 = bias[l15], bo1 = bias[16 + l15];
    ushort* hb = h1u + (size_t)b * H1ROWS * 64;
    const int pbase = tb / 2 + wv * 32 + kq * 2;
#pragma unroll
    for (int p = 0; p < 4; p++) {
        int pr = pbase + p * 8;
#pragma unroll
        for (int o = 0; o < 2; o++) {
            int oc = o * 16 + l15;
            float bo = o ? bo1 : bo0;
            float v0 = fmaxf(fmaxf(acc[p][o][0], acc[p][o][1]) + bo, 0.f);
            float v1 = fmaxf(fmaxf(acc[p][o][2], acc[p][o][3]) + bo, 0.f);
            ushort h0 = f2bf(v0), h1v = f2bf(v1);
            ushort l0 = f2bf(v0 - bf2f(h0)), l1 = f2bf(v1 - bf2f(h1v));
            size_t r0 = (size_t)(pr + 2) * 64, r1 = (size_t)(pr + 3) * 64;
            hb[r0 + oc] = h0; hb[r0 + 32 + oc] = l0;
            hb[r1 + oc] = h1v; hb[r1 + 32 + oc] = l1;
        }
    }
}

// ---------------------------------------------------------------------------
// conv2 (32->64,k5,p2)+relu+pool via MFMA. NO LDS, NO barriers.
// A-frags direct from global h1u (guard rows absorb padding), B-frags from
// fragment-contiguous w2p2. Block 256 = 4 waves; wave = 64 prepool x 64 oc.
// Grid (8,128). h2:[128][1024][64] fp32 ch-last.
__global__ __launch_bounds__(256, 3) void conv2_mfma(
    const ushort* __restrict__ h1u, const ushort* __restrict__ w2p2,
    const float* __restrict__ bias, float* __restrict__ h2)
{
    const int tid = threadIdx.x;
    const int b = blockIdx.y;
    const int tb = blockIdx.x * 256;
    const int lane = tid & 63;
    const int wv = __builtin_amdgcn_readfirstlane(tid >> 6);
    const int l15 = lane & 15;
    const int kq = lane >> 4;

    const ushort* hb = h1u + (size_t)b * H1ROWS * 64;
    const ushort* wb = w2p2 + l15 * 32 + kq * 8;

    f32x4 acc[4][4];
#pragma unroll
    for (int p = 0; p < 4; p++)
#pragma unroll
        for (int o = 0; o < 4; o++) acc[p][o] = (f32x4){0.f, 0.f, 0.f, 0.f};

#pragma unroll
    for (int kk = 0; kk < 5; kk++) {
        bf16x8 aHi[4], aLo[4];
#pragma unroll
        for (int p = 0; p < 4; p++) {
            size_t row = (size_t)(tb + wv * 64 + p * 16 + l15 + kk) * 64;
            aHi[p] = *(const bf16x8*)(hb + row + kq * 8);
            aLo[p] = *(const bf16x8*)(hb + row + 32 + kq * 8);
        }
#pragma unroll
        for (int ks = 0; ks < 3; ks++) {
            bf16x8 B0 = *(const bf16x8*)(wb + (kk * 3 + ks) * 2048);
            bf16x8 B1 = *(const bf16x8*)(wb + (kk * 3 + ks) * 2048 + 512);
            bf16x8 B2 = *(const bf16x8*)(wb + (kk * 3 + ks) * 2048 + 1024);
            bf16x8 B3 = *(const bf16x8*)(wb + (kk * 3 + ks) * 2048 + 1536);
#pragma unroll
            for (int p = 0; p < 4; p++) {
                bf16x8 a = (ks == 1) ? aLo[p] : aHi[p];
                acc[p][0] = __builtin_amdgcn_mfma_f32_16x16x32_bf16(a, B0, acc[p][0], 0, 0, 0);
                acc[p][1] = __builtin_amdgcn_mfma_f32_16x16x32_bf16(a, B1, acc[p][1], 0, 0, 0);
                acc[p][2] = __builtin_amdgcn_mfma_f32_16x16x32_bf16(a, B2, acc[p][2], 0, 0, 0);
                acc[p][3] = __builtin_amdgcn_mfma_f32_16x16x32_bf16(a, B3, acc[p][3], 0, 0, 0);
            }
        }
    }
    float* hb2 = h2 + (size_t)b * P2 * 64;
    const int pbase = tb / 2 + wv * 32 + kq * 2;
#pragma unroll
    for (int p = 0; p < 4; p++) {
        int pr = pbase + p * 8;
#pragma unroll
        for (int o = 0; o < 4; o++) {
            int oc = o * 16 + l15;
            float bo = bias[oc];
            float v0 = fmaxf(fmaxf(acc[p][o][0], acc[p][o][1]) + bo, 0.f);
            float v1 = fmaxf(fmaxf(acc[p][o][2], acc[p][o][3]) + bo, 0.f);
            hb2[(size_t)pr * 64 + oc] = v0;
            hb2[(size_t)(pr + 1) * 64 + oc] = v1;
        }
    }
}

// ---------------------------------------------------------------------------
// GAT projection, no LDS: each thread streams its own h2 row (256 B, every
// cacheline fully consumed), weights via wave-uniform s_load. Grid (4,128).
__global__ __launch_bounds__(256, 4) void gat_hw_kernel(
    const float* __restrict__ h2, const float* __restrict__ gwt,
    const float* __restrict__ att_src, const float* __restrict__ att_dst,
    float* __restrict__ hw, float* __restrict__ s_src, float* __restrict__ s_dst)
{
    const int tid = threadIdx.x, b = blockIdx.y;
    const int n = blockIdx.x * 256 + tid;
    const float* row = h2 + ((size_t)b * NNODE + n) * 64;

    float acc[16];
#pragma unroll
    for (int o = 0; o < 16; o++) acc[o] = 0.f;
#pragma unroll
    for (int q = 0; q < 16; q++) {
        float4 h4 = *(const float4*)(row + q * 4);
        float hv[4] = {h4.x, h4.y, h4.z, h4.w};
#pragma unroll
        for (int e = 0; e < 4; e++) {
            const float* wp = &gwt[(q * 4 + e) * 16];   // wave-uniform -> s_load
            float4 w0 = *(const float4*)(wp);
            float4 w1 = *(const float4*)(wp + 4);
            float4 w2 = *(const float4*)(wp + 8);
            float4 w3 = *(const float4*)(wp + 12);
            float hvv = hv[e];
            acc[0]  += hvv * w0.x; acc[1]  += hvv * w0.y; acc[2]  += hvv * w0.z; acc[3]  += hvv * w0.w;
            acc[4]  += hvv * w1.x; acc[5]  += hvv * w1.y; acc[6]  += hvv * w1.z; acc[7]  += hvv * w1.w;
            acc[8]  += hvv * w2.x; acc[9]  += hvv * w2.y; acc[10] += hvv * w2.z; acc[11] += hvv * w2.w;
            acc[12] += hvv * w3.x; acc[13] += hvv * w3.y; acc[14] += hvv * w3.z; acc[15] += hvv * w3.w;
        }
    }
    float ss = 0.f, sd = 0.f;
#pragma unroll
    for (int c = 0; c < 16; c++) { ss += acc[c] * att_src[c]; sd += acc[c] * att_dst[c]; }
    float4* hp = (float4*)(hw + ((size_t)b * NNODE + n) * 16);
    hp[0] = make_float4(acc[0], acc[1], acc[2], acc[3]);
    hp[1] = make_float4(acc[4], acc[5], acc[6], acc[7]);
    hp[2] = make_float4(acc[8], acc[9], acc[10], acc[11]);
    hp[3] = make_float4(acc[12], acc[13], acc[14], acc[15]);
    s_src[b * NNODE + n] = ss;
    s_dst[b * NNODE + n] = sd;
}

// ---------------------------------------------------------------------------
// rank: stable rank-count; candidate stream wave-uniform -> scalar cache.
__global__ __launch_bounds__(256) void rank_kernel(
    const float* __restrict__ s_src, float2* __restrict__ ski)
{
    const int tid = threadIdx.x, b = blockIdx.y;
    const int j = blockIdx.x * 256 + tid;
    const float k = s_src[b * NNODE + j];
    const float4* cand = (const float4*)(s_src + b * NNODE);
    int r = 0;
#pragma unroll 4
    for (int u4 = 0; u4 < 256; u4++) {
        const float4 c = cand[u4];          // uniform address -> s_load_dwordx4
        const int u = u4 * 4;
        r += (c.x < k || (c.x == k && (u + 0) < j));
        r += (c.y < k || (c.y == k && (u + 1) < j));
        r += (c.z < k || (c.z == k && (u + 2) < j));
        r += (c.w < k || (c.w == k && (u + 3) < j));
    }
    ski[b * NNODE + r] = make_float2(k, __int_as_float(j));
}

// ---------------------------------------------------------------------------
__device__ __forceinline__ void accum17(float* L, float wgt, const float4* hj)
{
    float4 a0 = hj[0], a1 = hj[1], a2 = hj[2], a3 = hj[3];
    L[0]  += wgt * a0.x; L[1]  += wgt * a0.y; L[2]  += wgt * a0.z; L[3]  += wgt * a0.w;
    L[4]  += wgt * a1.x; L[5]  += wgt * a1.y; L[6]  += wgt * a1.z; L[7]  += wgt * a1.w;
    L[8]  += wgt * a2.x; L[9]  += wgt * a2.y; L[10] += wgt * a2.z; L[11] += wgt * a2.w;
    L[12] += wgt * a3.x; L[13] += wgt * a3.y; L[14] += wgt * a3.z; L[15] += wgt * a3.w;
    L[16] += wgt;
}

// ---------------------------------------------------------------------------
// Fused prefix + apply, fully LDS-resident. One 512-thread block per batch.
__global__ __launch_bounds__(512) void attn_kernel(
    const float2* __restrict__ ski, const float* __restrict__ s_src,
    const float* __restrict__ s_dst, const float* __restrict__ hw,
    float* __restrict__ pooled)
{
    __shared__ float sPf[1025][17];     // 69700 B
    __shared__ float sPg[1025][17];     // 69700 B
    __shared__ float sks[1024];
    __shared__ float wsum[8][34];
    __shared__ float sred[8][16];
    const int tid = threadIdx.x, b = blockIdx.x;
    const int lane = tid & 63, wv = tid >> 6;

    const float2 kj0 = ski[b * NNODE + 2 * tid];
    const float2 kj1 = ski[b * NNODE + 2 * tid + 1];
    sks[2 * tid] = kj0.x;
    sks[2 * tid + 1] = kj1.x;
    __syncthreads();
    const float M = sks[1023];
    const float* hwb = hw + (size_t)b * NNODE * 16;
    const int j0 = __float_as_int(kj0.y), j1 = __float_as_int(kj1.y);
    const float f0 = __expf(kj0.x - M), g0 = __expf(0.2f * (kj0.x - M));
    const float f1 = __expf(kj1.x - M), g1 = __expf(0.2f * (kj1.x - M));
    const float4* hj0 = (const float4*)(hwb + (size_t)j0 * 16);
    const float4* hj1 = (const float4*)(hwb + (size_t)j1 * 16);

    float Lf[17], Lg[17];
#pragma unroll
    for (int c = 0; c < 17; c++) { Lf[c] = 0.f; Lg[c] = 0.f; }
    accum17(Lf, f0, hj0); accum17(Lg, g0, hj0);
    accum17(Lf, f1, hj1); accum17(Lg, g1, hj1);

#pragma unroll
    for (int s = 1; s < 64; s <<= 1) {
#pragma unroll
        for (int c = 0; c < 17; c++) {
            float of = __shfl_up(Lf[c], s);
            float og = __shfl_up(Lg[c], s);
            if (lane >= s) { Lf[c] += of; Lg[c] += og; }
        }
    }
    if (lane == 63) {
#pragma unroll
        for (int c = 0; c < 17; c++) { wsum[wv][c] = Lf[c]; wsum[wv][17 + c] = Lg[c]; }
    }
#pragma unroll
    for (int c = 0; c < 17; c++) {   // inclusive -> exclusive
        float ef = __shfl_up(Lf[c], 1);
        float eg = __shfl_up(Lg[c], 1);
        Lf[c] = (lane == 0) ? 0.f : ef;
        Lg[c] = (lane == 0) ? 0.f : eg;
    }
    __syncthreads();
#pragma unroll
    for (int c = 0; c < 17; c++) {
        float bf = 0.f, bg = 0.f;
        for (int w2 = 0; w2 < wv; w2++) { bf += wsum[w2][c]; bg += wsum[w2][17 + c]; }
        Lf[c] += bf; Lg[c] += bg;
    }

    const int p0 = 2 * tid;
#pragma unroll
    for (int c = 0; c < 17; c++) { sPf[p0][c] = Lf[c]; sPg[p0][c] = Lg[c]; }
    accum17(Lf, f0, hj0); accum17(Lg, g0, hj0);
#pragma unroll
    for (int c = 0; c < 17; c++) { sPf[p0 + 1][c] = Lf[c]; sPg[p0 + 1][c] = Lg[c]; }
    accum17(Lf, f1, hj1); accum17(Lg, g1, hj1);
    if (tid == 511) {
#pragma unroll
        for (int c = 0; c < 17; c++) { sPf[1024][c] = Lf[c]; sPg[1024][c] = Lg[c]; }
    }
    __syncthreads();

    float r[16];
#pragma unroll
    for (int c = 0; c < 16; c++) r[c] = 0.f;
#pragma unroll
    for (int e = 0; e < 2; e++) {
        const int i = e * 512 + tid;
        const float sdi = s_dst[b * NNODE + i];
        const float ssi = s_src[b * NNODE + i];
        const float eM = sdi + M;
        const float m_i = (eM >= 0.f) ? eM : 0.2f * eM;
        const float th = -sdi;
        int lo = 0, hi2 = 1024;
        while (lo < hi2) { int mid = (lo + hi2) >> 1; if (sks[mid] < th) lo = mid + 1; else hi2 = mid; }

        const float A  = __expf(eM - m_i);
        const float Bc = __expf(0.2f * eM - m_i);
        float acc[17];
#pragma unroll
        for (int c = 0; c < 17; c++) acc[c] = A * (sPf[1024][c] - sPf[lo][c]) + Bc * sPg[lo][c];

        float e2 = sdi + ssi;
        float el = (e2 >= 0.f) ? e2 : 0.2f * e2;
        float wii = __expf(el - m_i);
        const float4* hi4 = (const float4*)(hwb + (size_t)i * 16);
        accum17(acc, wii, hi4);

        float inv = 1.0f / acc[16];
#pragma unroll
        for (int c = 0; c < 16; c++) r[c] += acc[c] * inv;
    }
#pragma unroll
    for (int s = 32; s > 0; s >>= 1) {
#pragma unroll
        for (int c = 0; c < 16; c++) r[c] += __shfl_down(r[c], s);
    }
    if (lane == 0) {
#pragma unroll
        for (int c = 0; c < 16; c++) sred[wv][c] = r[c];
    }
    __syncthreads();
    if (tid < 16) {
        float t = 0.f;
#pragma unroll
        for (int w2 = 0; w2 < 8; w2++) t += sred[w2][tid];
        pooled[b * 16 + tid] = t;
    }
}

// ---------------------------------------------------------------------------
__global__ void final_kernel(
    const float* __restrict__ pooled, const float* __restrict__ gat_b,
    const float* __restrict__ fc_w, const float* __restrict__ fc_b,
    float* __restrict__ out)
{
    int b = threadIdx.x;
    if (b >= BATCH) return;
    float o0 = fc_b[0], o1 = fc_b[1];
#pragma unroll
    for (int d = 0; d < 16; d++) {
        float pv = pooled[b * 16 + d] * (1.0f / 1024.0f) + gat_b[d];
        o0 += pv * fc_w[d];
        o1 += pv * fc_w[16 + d];
    }
    out[2 * b] = o0;
    out[2 * b + 1] = o1;
}

// ---------------------------------------------------------------------------
extern "C" void kernel_launch(void* const* d_in, const int* in_sizes, int n_in,
                              void* d_out, int out_size, void* d_ws, size_t ws_size,
                              hipStream_t stream)
{
    (void)in_sizes; (void)n_in; (void)out_size; (void)ws_size;
    const float* x       = (const float*)d_in[0];
    const float* conv1_w = (const float*)d_in[1];
    const float* conv1_b = (const float*)d_in[2];
    const float* conv2_w = (const float*)d_in[3];
    const float* conv2_b = (const float*)d_in[4];
    const float* gat_w   = (const float*)d_in[5];
    const float* att_src = (const float*)d_in[6];
    const float* att_dst = (const float*)d_in[7];
    const float* gat_b   = (const float*)d_in[8];
    const float* fc_w    = (const float*)d_in[9];
    const float* fc_b    = (const float*)d_in[10];
    float* out = (float*)d_out;

    char* ws = (char*)d_ws;
    ushort* h1u   = (ushort*)(ws + OFF_H1U);
    float*  h2    = (float*)(ws + OFF_H2);
    float*  hw    = (float*)(ws + OFF_HW);
    ushort* w1p2  = (ushort*)(ws + OFF_W1P);
    ushort* w2p2  = (ushort*)(ws + OFF_W2P);
    float*  gwt   = (float*)(ws + OFF_GWT);
    float*  ssrc  = (float*)(ws + OFF_SSRC);
    float*  sdst  = (float*)(ws + OFF_SDST);
    float*  pool  = (float*)(ws + OFF_POOL);
    float2* ski   = (float2*)(ws + OFF_SKI);

    hipLaunchKernelGGL(prep_kernel, dim3(32), dim3(256), 0, stream,
                       conv1_w, conv2_w, gat_w, w1p2, w2p2, gwt, (uint*)h1u);
    hipLaunchKernelGGL(conv1_mfma, dim3(16, BATCH), dim3(256), 0, stream,
                       x, w1p2, conv1_b, h1u);
    hipLaunchKernelGGL(conv2_mfma, dim3(8, BATCH), dim3(256), 0, stream,
                       h1u, w2p2, conv2_b, h2);
    hipLaunchKernelGGL(gat_hw_kernel, dim3(4, BATCH), dim3(256), 0, stream,
                       h2, gwt, att_src, att_dst, hw, ssrc, sdst);
    hipLaunchKernelGGL(rank_kernel, dim3(4, BATCH), dim3(256), 0, stream,
                       ssrc, ski);
    hipLaunchKernelGGL(attn_kernel, dim3(BATCH), dim3(512), 0, stream,
                       ski, ssrc, sdst, hw, pool);
    hipLaunchKernelGGL(final_kernel, dim3(1), dim3(128), 0, stream,
                       pool, gat_b, fc_w, fc_b, out);
}

// Round 10
// 213.605 us; speedup vs baseline: 1.6126x; 1.1176x over previous
//
#include <hip/hip_runtime.h>
#include <cstddef>

// Problem dims
#define BATCH 128
#define T1 4096
#define P1 2048
#define T2 2048
#define P2 1024
#define NNODE 1024
#define H1ROWS 2052   // 2048 prepool rows + 2 guard rows each side

// Workspace layout (bytes).
//  - ski overlays h1u (h1u dead after conv2; rank runs after gat)
#define OFF_H1U  ((size_t)0)          // 128*2052*64*2 = 33,619,968
#define OFF_SKI  ((size_t)0)
#define OFF_H2U  ((size_t)33619968)   // 128*1024*128*2 = 33,554,432
#define OFF_HW   ((size_t)67174400)   // 8,388,608
#define OFF_SSRC ((size_t)75563008)   // 524,288
#define OFF_SDST ((size_t)76087296)   // 524,288
#define OFF_POOL ((size_t)76611584)   // 8,192
#define OFF_W1P  ((size_t)76619776)   // 5*2*1024*2  = 20,480
#define OFF_W2P  ((size_t)76640256)   // 5*3*2048*2 = 61,440
#define OFF_GB1  ((size_t)76701696)   // 4*16*32*2 = 4,096
#define OFF_GB2  ((size_t)76705792)   // 4,096
// end: 76,709,888 (within prior 77,078,528 budget)

typedef __attribute__((ext_vector_type(8))) short bf16x8;
typedef __attribute__((ext_vector_type(4))) float f32x4;

__device__ __forceinline__ ushort f2bf(float v) {
    uint u = __float_as_uint(v);
    uint r = u + 0x7FFFu + ((u >> 16) & 1u);
    return (ushort)(r >> 16);
}
__device__ __forceinline__ float bf2f(ushort h) {
    return __uint_as_float(((uint)h) << 16);
}

// ---------------------------------------------------------------------------
// prep: split-bf16 weight tables + gat B-operand tables + h1u guard zeroing.
// gb1[j][l15][ke]: j0=hi(gw[o][c0:32]) j1=hi(c32:64) j2=lo(c0:32) j3=lo(c32:64)
// gb2: cols: l15==0 -> (gw^T att_src)[c] split, l15==1 -> (gw^T att_dst)[c], else 0
__global__ void prep_kernel(const float* __restrict__ w1, const float* __restrict__ w2,
                            const float* __restrict__ gw,
                            const float* __restrict__ att_src, const float* __restrict__ att_dst,
                            ushort* __restrict__ w1p2, ushort* __restrict__ w2p2,
                            ushort* __restrict__ gb1, ushort* __restrict__ gb2,
                            uint* __restrict__ h1u32)
{
    const int idx0 = blockIdx.x * 256 + threadIdx.x;
    const int stride = 32 * 256;
    for (int idx = idx0; idx < 10240; idx += stride) {      // w1p2
        int kk = idx >> 11, q = idx & 2047;
        int ks = q >> 10, q2 = q & 1023;
        int o = q2 >> 9, r5 = q2 & 511;
        int l15 = r5 >> 5, ke = r5 & 31;
        int oc = o * 16 + l15, kp = ks * 32 + ke;
        ushort r = 0;
        if (kp < 51) {
            int c = (kp < 17) ? kp : (kp < 34 ? kp - 17 : kp - 34);
            float v = w1[(oc * 17 + c) * 5 + kk];
            ushort hi = f2bf(v);
            r = (kp < 34) ? hi : f2bf(v - bf2f(hi));
        }
        w1p2[idx] = r;
    }
    for (int idx = idx0; idx < 30720; idx += stride) {      // w2p2
        int kk = idx / 6144, rem = idx % 6144;
        int ks = rem >> 11, q2 = rem & 2047;
        int o = q2 >> 9, r5 = q2 & 511;
        int l15 = r5 >> 5, c = r5 & 31;
        int oc = o * 16 + l15;
        float v = w2[(oc * 32 + c) * 5 + kk];
        ushort hi = f2bf(v);
        w2p2[idx] = (ks < 2) ? hi : f2bf(v - bf2f(hi));
    }
    for (int idx = idx0; idx < 2048; idx += stride) {       // gb1
        int j = idx >> 9, l15 = (idx >> 5) & 15, ke = idx & 31;
        int c = (j & 1) * 32 + ke;
        float w = gw[l15 * 64 + c];
        ushort hi = f2bf(w);
        gb1[idx] = (j < 2) ? hi : f2bf(w - bf2f(hi));
    }
    for (int idx = idx0; idx < 2048; idx += stride) {       // gb2
        int j = idx >> 9, l15 = (idx >> 5) & 15, ke = idx & 31;
        ushort r = 0;
        if (l15 < 2) {
            int c = (j & 1) * 32 + ke;
            const float* av = (l15 == 0) ? att_src : att_dst;
            float a64 = 0.f;
            for (int o = 0; o < 16; o++) a64 += gw[o * 64 + c] * av[o];
            ushort hi = f2bf(a64);
            r = (j < 2) ? hi : f2bf(a64 - bf2f(hi));
        }
        gb2[idx] = r;
    }
    for (int idx = idx0; idx < 16384; idx += stride) {      // h1u guard rows = 0
        int b = idx >> 7, rr = (idx >> 5) & 3, col = idx & 31;
        int row = (rr < 2) ? rr : (2048 + rr);
        h1u32[((size_t)b * H1ROWS + row) * 32 + col] = 0;
    }
}

// ---------------------------------------------------------------------------
// conv1 (17->32,k5,p2)+relu+pool via MFMA. x -> h1u split-bf16 [128][2052][64].
// LDS x-tile XOR-swizzled; staging is row-per-thread (coalesced loads, uint4 writes).
__global__ __launch_bounds__(256, 4) void conv1_mfma(
    const float* __restrict__ x, const ushort* __restrict__ w1p2,
    const float* __restrict__ bias, ushort* __restrict__ h1u)
{
    __shared__ ushort sx[260 * 64];     // 33280 B, rows swizzled: e ^= (r&7)<<3
    const int tid = threadIdx.x;
    const int b = blockIdx.y;
    const int tb = blockIdx.x * 256;

    const float* xb = x + (size_t)b * (17 * T1);
    for (int r = tid; r < 260; r += 256) {
        int t = tb + r - 2;
        bool ok = (t >= 0 && t < T1);
        union { ushort u[64]; uint4 q[8]; } rb;
#pragma unroll
        for (int c = 0; c < 17; c++) {
            float v = ok ? xb[c * T1 + t] : 0.0f;
            ushort hi = f2bf(v);
            ushort lo = f2bf(v - bf2f(hi));
            rb.u[c] = hi; rb.u[17 + c] = lo; rb.u[34 + c] = hi;
        }
#pragma unroll
        for (int i = 51; i < 64; i++) rb.u[i] = 0;
        uint4* dst = (uint4*)sx;
#pragma unroll
        for (int c16 = 0; c16 < 8; c16++)
            dst[r * 8 + (c16 ^ (r & 7))] = rb.q[c16];
    }
    __syncthreads();

    const int lane = tid & 63;
    const int wv = __builtin_amdgcn_readfirstlane(tid >> 6);
    const int l15 = lane & 15;
    const int kq = lane >> 4;
    f32x4 acc[4][2];
#pragma unroll
    for (int p = 0; p < 4; p++)
#pragma unroll
        for (int o = 0; o < 2; o++) acc[p][o] = (f32x4){0.f, 0.f, 0.f, 0.f};

    const ushort* wb = w1p2 + l15 * 32 + kq * 8;
#pragma unroll
    for (int kk = 0; kk < 5; kk++) {
#pragma unroll
        for (int ks = 0; ks < 2; ks++) {
            bf16x8 B0 = *(const bf16x8*)(wb + (kk * 2 + ks) * 1024);
            bf16x8 B1 = *(const bf16x8*)(wb + (kk * 2 + ks) * 1024 + 512);
#pragma unroll
            for (int p = 0; p < 4; p++) {
                int lr = wv * 64 + p * 16 + l15 + kk;
                int soff = (ks * 32 + kq * 8) ^ ((lr & 7) << 3);
                bf16x8 a = *(const bf16x8*)&sx[lr * 64 + soff];
                acc[p][0] = __builtin_amdgcn_mfma_f32_16x16x32_bf16(a, B0, acc[p][0], 0, 0, 0);
                acc[p][1] = __builtin_amdgcn_mfma_f32_16x16x32_bf16(a, B1, acc[p][1], 0, 0, 0);
            }
        }
    }
    const float bo0 = bias[l15], bo1 = bias[16 + l15];
    ushort* hb = h1u + (size_t)b * H1ROWS * 64;
    const int pbase = tb / 2 + wv * 32 + kq * 2;
#pragma unroll
    for (int p = 0; p < 4; p++) {
        int pr = pbase + p * 8;
#pragma unroll
        for (int o = 0; o < 2; o++) {
            int oc = o * 16 + l15;
            float bo = o ? bo1 : bo0;
            float v0 = fmaxf(fmaxf(acc[p][o][0], acc[p][o][1]) + bo, 0.f);
            float v1 = fmaxf(fmaxf(acc[p][o][2], acc[p][o][3]) + bo, 0.f);
            ushort h0 = f2bf(v0), h1v = f2bf(v1);
            ushort l0 = f2bf(v0 - bf2f(h0)), l1 = f2bf(v1 - bf2f(h1v));
            size_t r0 = (size_t)(pr + 2) * 64, r1 = (size_t)(pr + 3) * 64;
            hb[r0 + oc] = h0; hb[r0 + 32 + oc] = l0;
            hb[r1 + oc] = h1v; hb[r1 + 32 + oc] = l1;
        }
    }
}

// ---------------------------------------------------------------------------
// conv2 (32->64,k5,p2)+relu+pool via MFMA. A staged once in swizzled LDS
// (pure uint4 copy of split-bf16 h1u), B from global fragment table.
// Output h2u split-bf16 [128][1024][128] rows [hi64|lo64].
__global__ __launch_bounds__(256, 4) void conv2_mfma(
    const ushort* __restrict__ h1u, const ushort* __restrict__ w2p2,
    const float* __restrict__ bias, ushort* __restrict__ h2u)
{
    __shared__ ushort sA[260 * 64];     // 33280 B, swizzled like conv1
    const int tid = threadIdx.x;
    const int b = blockIdx.y;
    const int tb = blockIdx.x * 256;

    const uint4* src = (const uint4*)(h1u + ((size_t)b * H1ROWS + tb) * 64);
    uint4* dst = (uint4*)sA;
    for (int idx = tid; idx < 2080; idx += 256) {
        int row = idx >> 3, c16 = idx & 7;
        dst[row * 8 + (c16 ^ (row & 7))] = src[idx];
    }
    __syncthreads();

    const int lane = tid & 63;
    const int wv = __builtin_amdgcn_readfirstlane(tid >> 6);
    const int l15 = lane & 15;
    const int kq = lane >> 4;

    const ushort* wb = w2p2 + l15 * 32 + kq * 8;
    f32x4 acc[4][4];
#pragma unroll
    for (int p = 0; p < 4; p++)
#pragma unroll
        for (int o = 0; o < 4; o++) acc[p][o] = (f32x4){0.f, 0.f, 0.f, 0.f};

#pragma unroll
    for (int kk = 0; kk < 5; kk++) {
        bf16x8 aHi[4], aLo[4];
#pragma unroll
        for (int p = 0; p < 4; p++) {
            int lr = wv * 64 + p * 16 + l15 + kk;
            int key = (lr & 7) << 3;
            aHi[p] = *(const bf16x8*)&sA[lr * 64 + ((kq * 8) ^ key)];
            aLo[p] = *(const bf16x8*)&sA[lr * 64 + ((32 + kq * 8) ^ key)];
        }
#pragma unroll
        for (int ks = 0; ks < 3; ks++) {
            bf16x8 B0 = *(const bf16x8*)(wb + (kk * 3 + ks) * 2048);
            bf16x8 B1 = *(const bf16x8*)(wb + (kk * 3 + ks) * 2048 + 512);
            bf16x8 B2 = *(const bf16x8*)(wb + (kk * 3 + ks) * 2048 + 1024);
            bf16x8 B3 = *(const bf16x8*)(wb + (kk * 3 + ks) * 2048 + 1536);
#pragma unroll
            for (int p = 0; p < 4; p++) {
                bf16x8 a = (ks == 1) ? aLo[p] : aHi[p];
                acc[p][0] = __builtin_amdgcn_mfma_f32_16x16x32_bf16(a, B0, acc[p][0], 0, 0, 0);
                acc[p][1] = __builtin_amdgcn_mfma_f32_16x16x32_bf16(a, B1, acc[p][1], 0, 0, 0);
                acc[p][2] = __builtin_amdgcn_mfma_f32_16x16x32_bf16(a, B2, acc[p][2], 0, 0, 0);
                acc[p][3] = __builtin_amdgcn_mfma_f32_16x16x32_bf16(a, B3, acc[p][3], 0, 0, 0);
            }
        }
    }
    ushort* h2b = h2u + (size_t)b * P2 * 128;
    const int pbase = tb / 2 + wv * 32 + kq * 2;
#pragma unroll
    for (int p = 0; p < 4; p++) {
        int pr = pbase + p * 8;
        ushort* r0 = h2b + (size_t)pr * 128;
        ushort* r1 = r0 + 128;
#pragma unroll
        for (int o = 0; o < 4; o++) {
            int oc = o * 16 + l15;
            float bo = bias[oc];
            float v0 = fmaxf(fmaxf(acc[p][o][0], acc[p][o][1]) + bo, 0.f);
            float v1 = fmaxf(fmaxf(acc[p][o][2], acc[p][o][3]) + bo, 0.f);
            ushort a0 = f2bf(v0), a1 = f2bf(v1);
            ushort l0 = f2bf(v0 - bf2f(a0)), l1 = f2bf(v1 - bf2f(a1));
            r0[oc] = a0; r0[64 + oc] = l0;
            r1[oc] = a1; r1[64 + oc] = l1;
        }
    }
}

// ---------------------------------------------------------------------------
// GAT projection via MFMA from split-bf16 h2u. No LDS, no barriers.
// hw = h2*gw^T; s_src/s_dst fused as a 2nd B-operand (gw^T att vectors).
// Grid (4,128) x 256; wave = 64 nodes.
__global__ __launch_bounds__(256) void gat_mfma(
    const ushort* __restrict__ h2u, const ushort* __restrict__ gb1,
    const ushort* __restrict__ gb2, float* __restrict__ hw,
    float* __restrict__ s_src, float* __restrict__ s_dst)
{
    const int tid = threadIdx.x, b = blockIdx.y;
    const int lane = tid & 63, wv = tid >> 6, l15 = lane & 15, kq = lane >> 4;
    const int wbase = blockIdx.x * 256 + wv * 64;
    const ushort* hb = h2u + ((size_t)b * NNODE + wbase) * 128;

    bf16x8 A[4][4];
#pragma unroll
    for (int rg = 0; rg < 4; rg++)
#pragma unroll
        for (int ac = 0; ac < 4; ac++)
            A[rg][ac] = *(const bf16x8*)&hb[(size_t)(rg * 16 + l15) * 128 + ac * 32 + kq * 8];

    bf16x8 B1v[4], B2v[4];
#pragma unroll
    for (int j = 0; j < 4; j++) {
        B1v[j] = *(const bf16x8*)&gb1[j * 512 + l15 * 32 + kq * 8];
        B2v[j] = *(const bf16x8*)&gb2[j * 512 + l15 * 32 + kq * 8];
    }

    float* hwb = hw + (size_t)b * NNODE * 16;
#pragma unroll
    for (int rg = 0; rg < 4; rg++) {
        f32x4 h = (f32x4){0.f, 0.f, 0.f, 0.f};
        f32x4 s = (f32x4){0.f, 0.f, 0.f, 0.f};
        h = __builtin_amdgcn_mfma_f32_16x16x32_bf16(A[rg][0], B1v[0], h, 0, 0, 0);
        s = __builtin_amdgcn_mfma_f32_16x16x32_bf16(A[rg][0], B2v[0], s, 0, 0, 0);
        h = __builtin_amdgcn_mfma_f32_16x16x32_bf16(A[rg][1], B1v[1], h, 0, 0, 0);
        s = __builtin_amdgcn_mfma_f32_16x16x32_bf16(A[rg][1], B2v[1], s, 0, 0, 0);
        h = __builtin_amdgcn_mfma_f32_16x16x32_bf16(A[rg][2], B1v[0], h, 0, 0, 0);
        s = __builtin_amdgcn_mfma_f32_16x16x32_bf16(A[rg][2], B2v[0], s, 0, 0, 0);
        h = __builtin_amdgcn_mfma_f32_16x16x32_bf16(A[rg][3], B1v[1], h, 0, 0, 0);
        s = __builtin_amdgcn_mfma_f32_16x16x32_bf16(A[rg][3], B2v[1], s, 0, 0, 0);
        h = __builtin_amdgcn_mfma_f32_16x16x32_bf16(A[rg][0], B1v[2], h, 0, 0, 0);
        s = __builtin_amdgcn_mfma_f32_16x16x32_bf16(A[rg][0], B2v[2], s, 0, 0, 0);
        h = __builtin_amdgcn_mfma_f32_16x16x32_bf16(A[rg][1], B1v[3], h, 0, 0, 0);
        s = __builtin_amdgcn_mfma_f32_16x16x32_bf16(A[rg][1], B2v[3], s, 0, 0, 0);

        const int n0 = wbase + rg * 16 + kq * 4;
#pragma unroll
        for (int reg = 0; reg < 4; reg++)
            hwb[(size_t)(n0 + reg) * 16 + l15] = h[reg];
        if (l15 == 0) {
#pragma unroll
            for (int reg = 0; reg < 4; reg++) s_src[b * NNODE + n0 + reg] = s[reg];
        } else if (l15 == 1) {
#pragma unroll
            for (int reg = 0; reg < 4; reg++) s_dst[b * NNODE + n0 + reg] = s[reg];
        }
    }
}

// ---------------------------------------------------------------------------
// rank: stable rank-count; candidate stream wave-uniform -> scalar cache.
__global__ __launch_bounds__(256) void rank_kernel(
    const float* __restrict__ s_src, float2* __restrict__ ski)
{
    const int tid = threadIdx.x, b = blockIdx.y;
    const int j = blockIdx.x * 256 + tid;
    const float k = s_src[b * NNODE + j];
    const float4* cand = (const float4*)(s_src + b * NNODE);
    int r = 0;
#pragma unroll 4
    for (int u4 = 0; u4 < 256; u4++) {
        const float4 c = cand[u4];          // uniform address -> s_load_dwordx4
        const int u = u4 * 4;
        r += (c.x < k || (c.x == k && (u + 0) < j));
        r += (c.y < k || (c.y == k && (u + 1) < j));
        r += (c.z < k || (c.z == k && (u + 2) < j));
        r += (c.w < k || (c.w == k && (u + 3) < j));
    }
    ski[b * NNODE + r] = make_float2(k, __int_as_float(j));
}

// ---------------------------------------------------------------------------
__device__ __forceinline__ void accum17(float* L, float wgt, const float4* hj)
{
    float4 a0 = hj[0], a1 = hj[1], a2 = hj[2], a3 = hj[3];
    L[0]  += wgt * a0.x; L[1]  += wgt * a0.y; L[2]  += wgt * a0.z; L[3]  += wgt * a0.w;
    L[4]  += wgt * a1.x; L[5]  += wgt * a1.y; L[6]  += wgt * a1.z; L[7]  += wgt * a1.w;
    L[8]  += wgt * a2.x; L[9]  += wgt * a2.y; L[10] += wgt * a2.z; L[11] += wgt * a2.w;
    L[12] += wgt * a3.x; L[13] += wgt * a3.y; L[14] += wgt * a3.z; L[15] += wgt * a3.w;
    L[16] += wgt;
}

// ---------------------------------------------------------------------------
// Fused prefix + apply, fully LDS-resident. One 512-thread block per batch.
__global__ __launch_bounds__(512) void attn_kernel(
    const float2* __restrict__ ski, const float* __restrict__ s_src,
    const float* __restrict__ s_dst, const float* __restrict__ hw,
    float* __restrict__ pooled)
{
    __shared__ float sPf[1025][17];     // 69700 B
    __shared__ float sPg[1025][17];     // 69700 B
    __shared__ float sks[1024];
    __shared__ float wsum[8][34];
    __shared__ float sred[8][16];
    const int tid = threadIdx.x, b = blockIdx.x;
    const int lane = tid & 63, wv = tid >> 6;

    const float2 kj0 = ski[b * NNODE + 2 * tid];
    const float2 kj1 = ski[b * NNODE + 2 * tid + 1];
    sks[2 * tid] = kj0.x;
    sks[2 * tid + 1] = kj1.x;
    __syncthreads();
    const float M = sks[1023];
    const float* hwb = hw + (size_t)b * NNODE * 16;
    const int j0 = __float_as_int(kj0.y), j1 = __float_as_int(kj1.y);
    const float f0 = __expf(kj0.x - M), g0 = __expf(0.2f * (kj0.x - M));
    const float f1 = __expf(kj1.x - M), g1 = __expf(0.2f * (kj1.x - M));
    const float4* hj0 = (const float4*)(hwb + (size_t)j0 * 16);
    const float4* hj1 = (const float4*)(hwb + (size_t)j1 * 16);

    float Lf[17], Lg[17];
#pragma unroll
    for (int c = 0; c < 17; c++) { Lf[c] = 0.f; Lg[c] = 0.f; }
    accum17(Lf, f0, hj0); accum17(Lg, g0, hj0);
    accum17(Lf, f1, hj1); accum17(Lg, g1, hj1);

#pragma unroll
    for (int s = 1; s < 64; s <<= 1) {
#pragma unroll
        for (int c = 0; c < 17; c++) {
            float of = __shfl_up(Lf[c], s);
            float og = __shfl_up(Lg[c], s);
            if (lane >= s) { Lf[c] += of; Lg[c] += og; }
        }
    }
    if (lane == 63) {
#pragma unroll
        for (int c = 0; c < 17; c++) { wsum[wv][c] = Lf[c]; wsum[wv][17 + c] = Lg[c]; }
    }
#pragma unroll
    for (int c = 0; c < 17; c++) {   // inclusive -> exclusive
        float ef = __shfl_up(Lf[c], 1);
        float eg = __shfl_up(Lg[c], 1);
        Lf[c] = (lane == 0) ? 0.f : ef;
        Lg[c] = (lane == 0) ? 0.f : eg;
    }
    __syncthreads();
#pragma unroll
    for (int c = 0; c < 17; c++) {
        float bf = 0.f, bg = 0.f;
        for (int w2 = 0; w2 < wv; w2++) { bf += wsum[w2][c]; bg += wsum[w2][17 + c]; }
        Lf[c] += bf; Lg[c] += bg;
    }

    const int p0 = 2 * tid;
#pragma unroll
    for (int c = 0; c < 17; c++) { sPf[p0][c] = Lf[c]; sPg[p0][c] = Lg[c]; }
    accum17(Lf, f0, hj0); accum17(Lg, g0, hj0);
#pragma unroll
    for (int c = 0; c < 17; c++) { sPf[p0 + 1][c] = Lf[c]; sPg[p0 + 1][c] = Lg[c]; }
    accum17(Lf, f1, hj1); accum17(Lg, g1, hj1);
    if (tid == 511) {
#pragma unroll
        for (int c = 0; c < 17; c++) { sPf[1024][c] = Lf[c]; sPg[1024][c] = Lg[c]; }
    }
    __syncthreads();

    float r[16];
#pragma unroll
    for (int c = 0; c < 16; c++) r[c] = 0.f;
#pragma unroll
    for (int e = 0; e < 2; e++) {
        const int i = e * 512 + tid;
        const float sdi = s_dst[b * NNODE + i];
        const float ssi = s_src[b * NNODE + i];
        const float eM = sdi + M;
        const float m_i = (eM >= 0.f) ? eM : 0.2f * eM;
        const float th = -sdi;
        int lo = 0, hi2 = 1024;
        while (lo < hi2) { int mid = (lo + hi2) >> 1; if (sks[mid] < th) lo = mid + 1; else hi2 = mid; }

        const float A  = __expf(eM - m_i);
        const float Bc = __expf(0.2f * eM - m_i);
        float acc[17];
#pragma unroll
        for (int c = 0; c < 17; c++) acc[c] = A * (sPf[1024][c] - sPf[lo][c]) + Bc * sPg[lo][c];

        float e2 = sdi + ssi;
        float el = (e2 >= 0.f) ? e2 : 0.2f * e2;
        float wii = __expf(el - m_i);
        const float4* hi4 = (const float4*)(hwb + (size_t)i * 16);
        accum17(acc, wii, hi4);

        float inv = 1.0f / acc[16];
#pragma unroll
        for (int c = 0; c < 16; c++) r[c] += acc[c] * inv;
    }
#pragma unroll
    for (int s = 32; s > 0; s >>= 1) {
#pragma unroll
        for (int c = 0; c < 16; c++) r[c] += __shfl_down(r[c], s);
    }
    if (lane == 0) {
#pragma unroll
        for (int c = 0; c < 16; c++) sred[wv][c] = r[c];
    }
    __syncthreads();
    if (tid < 16) {
        float t = 0.f;
#pragma unroll
        for (int w2 = 0; w2 < 8; w2++) t += sred[w2][tid];
        pooled[b * 16 + tid] = t;
    }
}

// ---------------------------------------------------------------------------
__global__ void final_kernel(
    const float* __restrict__ pooled, const float* __restrict__ gat_b,
    const float* __restrict__ fc_w, const float* __restrict__ fc_b,
    float* __restrict__ out)
{
    int b = threadIdx.x;
    if (b >= BATCH) return;
    float o0 = fc_b[0], o1 = fc_b[1];
#pragma unroll
    for (int d = 0; d < 16; d++) {
        float pv = pooled[b * 16 + d] * (1.0f / 1024.0f) + gat_b[d];
        o0 += pv * fc_w[d];
        o1 += pv * fc_w[16 + d];
    }
    out[2 * b] = o0;
    out[2 * b + 1] = o1;
}

// ---------------------------------------------------------------------------
extern "C" void kernel_launch(void* const* d_in, const int* in_sizes, int n_in,
                              void* d_out, int out_size, void* d_ws, size_t ws_size,
                              hipStream_t stream)
{
    (void)in_sizes; (void)n_in; (void)out_size; (void)ws_size;
    const float* x       = (const float*)d_in[0];
    const float* conv1_w = (const float*)d_in[1];
    const float* conv1_b = (const float*)d_in[2];
    const float* conv2_w = (const float*)d_in[3];
    const float* conv2_b = (const float*)d_in[4];
    const float* gat_w   = (const float*)d_in[5];
    const float* att_src = (const float*)d_in[6];
    const float* att_dst = (const float*)d_in[7];
    const float* gat_b   = (const float*)d_in[8];
    const float* fc_w    = (const float*)d_in[9];
    const float* fc_b    = (const float*)d_in[10];
    float* out = (float*)d_out;

    char* ws = (char*)d_ws;
    ushort* h1u   = (ushort*)(ws + OFF_H1U);
    ushort* h2u   = (ushort*)(ws + OFF_H2U);
    float*  hw    = (float*)(ws + OFF_HW);
    ushort* w1p2  = (ushort*)(ws + OFF_W1P);
    ushort* w2p2  = (ushort*)(ws + OFF_W2P);
    ushort* gb1   = (ushort*)(ws + OFF_GB1);
    ushort* gb2   = (ushort*)(ws + OFF_GB2);
    float*  ssrc  = (float*)(ws + OFF_SSRC);
    float*  sdst  = (float*)(ws + OFF_SDST);
    float*  pool  = (float*)(ws + OFF_POOL);
    float2* ski   = (float2*)(ws + OFF_SKI);

    hipLaunchKernelGGL(prep_kernel, dim3(32), dim3(256), 0, stream,
                       conv1_w, conv2_w, gat_w, att_src, att_dst,
                       w1p2, w2p2, gb1, gb2, (uint*)h1u);
    hipLaunchKernelGGL(conv1_mfma, dim3(16, BATCH), dim3(256), 0, stream,
                       x, w1p2, conv1_b, h1u);
    hipLaunchKernelGGL(conv2_mfma, dim3(8, BATCH), dim3(256), 0, stream,
                       h1u, w2p2, conv2_b, h2u);
    hipLaunchKernelGGL(gat_mfma, dim3(4, BATCH), dim3(256), 0, stream,
                       h2u, gb1, gb2, hw, ssrc, sdst);
    hipLaunchKernelGGL(rank_kernel, dim3(4, BATCH), dim3(256), 0, stream,
                       ssrc, ski);
    hipLaunchKernelGGL(attn_kernel, dim3(BATCH), dim3(512), 0, stream,
                       ski, ssrc, sdst, hw, pool);
    hipLaunchKernelGGL(final_kernel, dim3(1), dim3(128), 0, stream,
                       pool, gat_b, fc_w, fc_b, out);
}